// Round 7
// baseline (319.274 us; speedup 1.0000x reference)
//
#include <hip/hip_runtime.h>
#include <hip/hip_bf16.h>

// MultiHeadAttention: x(8,256,32,32) -> qkv proj -> global-softmax attention -> out proj.
//   g1 (gemm_nt mode 0): scaled_t[n,l,o] = (x_t . w_in + b_in) * SCALE       (K=256)
//   attn_fused:          out_tt[n,m,h*256+d] = Sum_l exp(q_l.k_m) v[d,l]  (UNNORMALIZED)
//                        Z[nh] = Sum exp(q.k)
//   g4 (gemm_nt mode 4): out[n,c,m] = w_out . (out_tt/Z) + b_out
// Global softmax: att ~ N(0,0.17^2) -> exp() without max-subtraction is safe.
// R7: attn_fused was LDS-pipe-bound (R6: 74 b128 reads/wave/iter = 288k cyc/CU = the
//     whole 120 us). Rebuilt around 32x32x16 MFMA with K in REGISTERS (loaded once),
//     Q A-frags direct from global (L1/XCD-L2), V via global_load_lds, P stride-68 pad.
//     LDS ops per wave per iter: 98 -> ~28. XCD swizzle (R6) retained.

typedef __bf16 bf16x8 __attribute__((ext_vector_type(8)));
typedef __bf16 bf16x4 __attribute__((ext_vector_type(4)));
typedef float f32x4 __attribute__((ext_vector_type(4)));
typedef float f32x16 __attribute__((ext_vector_type(16)));
typedef __hip_bfloat16 bf16;

__device__ __forceinline__ void async_copy16(const void* g, void* s) {
    __builtin_amdgcn_global_load_lds(
        (const __attribute__((address_space(1))) unsigned int*)g,
        (__attribute__((address_space(3))) unsigned int*)s, 16, 0, 0);
}

__device__ __forceinline__ bf16x8 scale8(bf16x8 v, float s) {
    bf16x8 r;
#pragma unroll
    for (int e = 0; e < 8; ++e) r[e] = (__bf16)((float)v[e] * s);
    return r;
}

// ---------------------------------------------------------------------------
// Generic NT bf16 GEMM, 128x128 tile, BK=64, 256 threads (2x2 waves).
// Register-prefetch pipelined K-loop (R4), XOR-swizzled LDS (R3, 0 conflicts).
// mode 0: C=bf16, (acc + bias[col]) * scale
// mode 3: C=f32,  acc + bias[row]
// mode 4: C=f32,  acc + bias[row]; B scaled by 1/Zp[zn*8 + k/256] during staging
__global__ __launch_bounds__(256)
void gemm_nt(const bf16* __restrict__ A, const bf16* __restrict__ B, void* __restrict__ Cvoid,
             int M, int N, int K, int lda, int ldb, int ldc,
             long asn, long ash, long bsn, long bsh, long csn, long csh,
             int H, int mode, const float* __restrict__ bias, const float* __restrict__ Zp,
             float scale)
{
    __shared__ __align__(16) bf16 smem[17408];
    bf16* Alds = smem;
    bf16* Blds = smem + 8192;

    const int tid  = threadIdx.x;
    const int wave = tid >> 6;
    const int lane = tid & 63;
    const int z  = blockIdx.z;
    const int zn = z / H, zh = z % H;

    const bf16* Ab = A + zn * asn + zh * ash;
    const bf16* Bb = B + zn * bsn + zh * bsh;

    const long tM = (long)blockIdx.y * 128;
    const long tN = (long)blockIdx.x * 128;

    const int wr   = (wave >> 1) * 64;
    const int wc   = (wave & 1) * 64;
    const int l15  = lane & 15;
    const int quad = lane >> 4;

    f32x4 acc[4][4] = {};

    const int kiters = K >> 6;
    const bool regB = (mode == 4);

#pragma unroll
    for (int i = 0; i < 4; ++i) {
        const int flat = i * 256 + tid;
        const int row  = flat >> 3;
        const int kcs  = (flat & 7) ^ (row & 7);
        async_copy16(Ab + (tM + row) * (long)lda + kcs * 8,
                     (char*)Alds + (long)(i * 256 + wave * 64) * 16);
        if (!regB) {
            async_copy16(Bb + (tN + row) * (long)ldb + kcs * 8,
                         (char*)Blds + (long)(i * 256 + wave * 64) * 16);
        }
    }
    if (regB) {
        const float zi0 = 1.0f / Zp[zn * 8];
#pragma unroll
        for (int i = 0; i < 4; ++i) {
            const int flat = i * 256 + tid;
            const int row  = flat >> 3;
            const int kcs  = (flat & 7) ^ (row & 7);
            bf16x8 b = *(const bf16x8*)(Bb + (tN + row) * (long)ldb + kcs * 8);
            *(bf16x8*)((char*)Blds + (long)flat * 16) = scale8(b, zi0);
        }
    }

    bf16x8 pfA[4], pfB[4];
    for (int kt = 0; kt < kiters; ++kt) {
        __syncthreads();
        const bool has_next = (kt + 1 < kiters);
        float zin = 1.0f;
        if (has_next) {
            const long kof = (long)(kt + 1) * 64;
            if (regB) zin = 1.0f / Zp[zn * 8 + ((kt + 1) >> 2)];
#pragma unroll
            for (int i = 0; i < 4; ++i) {
                const int flat = i * 256 + tid;
                const int row  = flat >> 3;
                const int kcs  = (flat & 7) ^ (row & 7);
                pfA[i] = *(const bf16x8*)(Ab + (tM + row) * (long)lda + kof + kcs * 8);
                pfB[i] = *(const bf16x8*)(Bb + (tN + row) * (long)ldb + kof + kcs * 8);
            }
        }
#pragma unroll
        for (int kk = 0; kk < 2; ++kk) {
            bf16x8 af[4], bfv[4];
#pragma unroll
            for (int i = 0; i < 4; ++i) {
                const int r = wr + i * 16 + l15;
                af[i] = *(const bf16x8*)(Alds + r * 64 + ((kk * 4 + quad) ^ (r & 7)) * 8);
            }
#pragma unroll
            for (int j = 0; j < 4; ++j) {
                const int r = wc + j * 16 + l15;
                bfv[j] = *(const bf16x8*)(Blds + r * 64 + ((kk * 4 + quad) ^ (r & 7)) * 8);
            }
#pragma unroll
            for (int i = 0; i < 4; ++i)
#pragma unroll
                for (int j = 0; j < 4; ++j)
                    acc[i][j] = __builtin_amdgcn_mfma_f32_16x16x32_bf16(af[i], bfv[j], acc[i][j], 0, 0, 0);
        }
        if (has_next) {
            __builtin_amdgcn_sched_barrier(0);
            __builtin_amdgcn_s_barrier();
            __builtin_amdgcn_sched_barrier(0);
#pragma unroll
            for (int i = 0; i < 4; ++i) {
                const int flat = i * 256 + tid;
                *(bf16x8*)((char*)Alds + (long)flat * 16) = pfA[i];
                *(bf16x8*)((char*)Blds + (long)flat * 16) = regB ? scale8(pfB[i], zin) : pfB[i];
            }
        }
    }

    if (mode >= 3) {
        float* C = (float*)Cvoid + zn * csn + zh * csh;
#pragma unroll
        for (int i = 0; i < 4; ++i)
#pragma unroll
            for (int j = 0; j < 4; ++j)
#pragma unroll
                for (int r = 0; r < 4; ++r) {
                    const long row = tM + wr + i * 16 + quad * 4 + r;
                    const long col = tN + wc + j * 16 + l15;
                    C[row * (long)ldc + col] = acc[i][j][r] + bias[row];
                }
    } else {
        bf16* Cb = (bf16*)Cvoid + zn * csn + zh * csh + tM * (long)ldc + tN;
        __syncthreads();
#pragma unroll
        for (int i = 0; i < 4; ++i)
#pragma unroll
            for (int j = 0; j < 4; ++j)
#pragma unroll
                for (int r = 0; r < 4; ++r) {
                    const int row = wr + i * 16 + quad * 4 + r;
                    const int col = wc + j * 16 + l15;
                    smem[row * 136 + col] = __float2bfloat16((acc[i][j][r] + bias[col]) * scale);
                }
        __syncthreads();
#pragma unroll
        for (int k = 0; k < 8; ++k) {
            const int fc  = k * 256 + tid;
            const int row = fc >> 4, cc = fc & 15;
            const f32x4 val = *(const f32x4*)((const char*)smem + row * 272 + cc * 16);
            *(f32x4*)((char*)(Cb + (long)row * ldc) + cc * 16) = val;
        }
    }
}

// ---------------------------------------------------------------------------
// Fused attention v3 (32x32x16 MFMA, register-heavy, LDS-light).
// Block = (64-key m-tile, nh); grid 1024, XCD-swizzled. Per l-tile (64 queries):
//   S: wave (wl,wm) computes 32l x 32m; Q A-frags DIRECT from global (16 loads,
//      L1-resident bursts), K B-frags preloaded in 64 VGPRs (reused all 16 iters).
//      Zero LDS traffic except the P write (4 ds_write_b64, stride-68 pad).
//   O: d-split (wave = 64m x 64d); P read as b64 pairs (2-way, free), V read b128
//      from async-staged XOR-swizzled tile (4-way residual, structural to 128B rows).
// Barriers: B1 raw s_barrier (prev O reads consumed; Q prefetch stays in flight),
//   B2 __syncthreads (drains async V, covered by S-phase compute).
// Fragment layouts (32x32x16): A/B lane holds [row=lane&31][k=(lane>>5)*8+j];
//   C/D: col=lane&31, row=(reg&3)+8*(reg>>2)+4*(lane>>5) (guide m74/m101).
__global__ __launch_bounds__(256, 2)
void attn_fused(const bf16* __restrict__ scaled_t, const bf16* __restrict__ v2,
                bf16* __restrict__ out_tt, float* __restrict__ Z)
{
    __shared__ __align__(16) bf16 smem[20752];
    bf16* Vs = smem;                      // 256d x 64l, chunk-XOR   [0, 16384)
    bf16* Ps = smem + 16384;              // 64m x stride68          [16384, 20736)
    float* Zs = (float*)(smem + 20736);   // 4 floats

    const int tid  = threadIdx.x;
    const int wave = tid >> 6, lane = tid & 63;
    const int l31  = lane & 31, hw = lane >> 5;

    const int b   = blockIdx.x;
    const int xcd = b & 7, s = b >> 3;
    const int nh  = xcd * 8 + (s >> 4);   // xcd == n: each XCD streams one batch image
    const int mt_ = s & 15;
    const int n   = nh >> 3, h = nh & 7;
    const long m0 = (long)mt_ * 64;

    const bf16* Qb = scaled_t + (long)n * 6291456 + h * 768;
    const bf16* Kb = Qb + 256;
    const bf16* Vb = v2 + (long)nh * 262144;

    const int wl = wave & 1;              // S-phase l-half
    const int wm = wave >> 1;             // S-phase m-half

    // K fragments resident in registers for the whole block (reused 16x).
    bf16x8 Kf[16];
    {
        const bf16* Krow = Kb + (m0 + wm * 32 + l31) * 6144;
#pragma unroll
        for (int w = 0; w < 16; ++w)
            Kf[w] = *(const bf16x8*)(Krow + w * 16 + hw * 8);
    }

    const bf16* Qrow = Qb + (wl * 32 + l31) * 6144;
    bf16x8 Qf[16];
#pragma unroll
    for (int w = 0; w < 16; ++w)
        Qf[w] = *(const bf16x8*)(Qrow + w * 16 + hw * 8);

    f32x16 accO[2][2] = {};
    float zsum = 0.0f;

    for (int lt = 0; lt < 16; ++lt) {
        const long l0 = (long)lt * 64;

        // B1 raw barrier: prev-iter O-phase ds_reads are consumed (lgkm-waited before
        // their MFMAs), so overwriting Vs/Ps below is safe; Qf prefetch loads and this
        // iter's K/Q traffic stay in flight (no vmcnt drain).
        __builtin_amdgcn_sched_barrier(0);
        __builtin_amdgcn_s_barrier();
        __builtin_amdgcn_sched_barrier(0);

        // Stage V tile (256d x 64l) via global_load_lds, XOR-swizzled source chunks.
#pragma unroll
        for (int i = 0; i < 8; ++i) {
            const int flat = i * 256 + tid;
            const int d    = flat >> 3;
            const int ch   = flat & 7;
            async_copy16(Vb + (long)d * 1024 + l0 + ((ch ^ (d & 7)) * 8),
                         (char*)Vs + (long)(i * 256 + wave * 64) * 16);
        }

        // S-phase: 32l x 32m per wave, operands entirely in registers.
        f32x16 accS = {};
#pragma unroll
        for (int w = 0; w < 16; ++w)
            accS = __builtin_amdgcn_mfma_f32_32x32x16_bf16(Qf[w], Kf[w], accS, 0, 0, 0);

        // exp -> P[m][l] (stride 68; b64 writes), accumulate zsum.
        {
            bf16* prow = Ps + (wm * 32 + l31) * 68 + wl * 32 + 4 * hw;
#pragma unroll
            for (int g = 0; g < 4; ++g) {
                bf16x4 pk;
#pragma unroll
                for (int e = 0; e < 4; ++e) {
                    const float v = __expf(accS[g * 4 + e]);
                    zsum += v;
                    pk[e] = (__bf16)v;
                }
                *(bf16x4*)(prow + 8 * g) = pk;
            }
        }

        // B2: drains async V (vmcnt, covered by S) + P writes (lgkm).
        __syncthreads();

        // Prefetch next iter's Q frags; consumed after the next raw B1.
        if (lt < 15) {
            const bf16* Qn = Qrow + (l0 + 64) * 6144;
#pragma unroll
            for (int w = 0; w < 16; ++w)
                Qf[w] = *(const bf16x8*)(Qn + w * 16 + hw * 8);
        }

        // O-phase: wave computes 64m x 64d (d = wave*64..+64) over k=64 l.
#pragma unroll
        for (int kw = 0; kw < 4; ++kw) {
            bf16x8 pf[2], vf[2];
#pragma unroll
            for (int mt = 0; mt < 2; ++mt) {
                const bf16* pp = Ps + (mt * 32 + l31) * 68 + kw * 16 + hw * 8;
                const bf16x4 lo = *(const bf16x4*)pp;
                const bf16x4 hi = *(const bf16x4*)(pp + 4);
#pragma unroll
                for (int e = 0; e < 4; ++e) { pf[mt][e] = lo[e]; pf[mt][4 + e] = hi[e]; }
            }
#pragma unroll
            for (int dt = 0; dt < 2; ++dt) {
                const int d    = wave * 64 + dt * 32 + l31;
                const int slot = (kw * 2 + hw) ^ (d & 7);
                vf[dt] = *(const bf16x8*)(Vs + d * 64 + slot * 8);
            }
#pragma unroll
            for (int mt = 0; mt < 2; ++mt)
#pragma unroll
                for (int dt = 0; dt < 2; ++dt)
                    accO[mt][dt] = __builtin_amdgcn_mfma_f32_32x32x16_bf16(
                        pf[mt], vf[dt], accO[mt][dt], 0, 0, 0);
        }
    }

    __syncthreads();   // last O reads done; Vs/Ps become the C-stage

    // Z reduction: wave shuffle -> Zs -> one atomicAdd.
#pragma unroll
    for (int o = 32; o > 0; o >>= 1) zsum += __shfl_down(zsum, o);
    if (lane == 0) Zs[wave] = zsum;

    // Stage C (64m x 256d, stride 264) then b128 coalesced stores.
    bf16* Cs = smem;
#pragma unroll
    for (int mt = 0; mt < 2; ++mt)
#pragma unroll
        for (int dt = 0; dt < 2; ++dt)
#pragma unroll
            for (int r = 0; r < 16; ++r) {
                const int m = mt * 32 + (r & 3) + 8 * (r >> 2) + 4 * hw;
                const int d = wave * 64 + dt * 32 + l31;
                Cs[m * 264 + d] = __float2bfloat16(accO[mt][dt][r]);
            }
    __syncthreads();
    if (tid == 0) atomicAdd(Z + nh, (Zs[0] + Zs[1]) + (Zs[2] + Zs[3]));

    bf16* Ob = out_tt + (long)n * 2097152 + m0 * 2048 + h * 256;
#pragma unroll
    for (int k = 0; k < 8; ++k) {
        const int flat = k * 256 + tid;
        const int row  = flat >> 5;
        const int c    = flat & 31;
        const f32x4 val = *(const f32x4*)((const char*)Cs + row * 528 + c * 16);
        *(f32x4*)((char*)(Ob + (long)row * 2048) + c * 16) = val;
    }
}

// ---------------------------------------------------------------------------
__global__ void prep_convert(const float* __restrict__ w_in, const float* __restrict__ w_out,
                             bf16* __restrict__ w_in_b, bf16* __restrict__ w_out_b,
                             float* __restrict__ Z)
{
    const long gid = (long)blockIdx.x * 256 + threadIdx.x;
    if (blockIdx.x == 0 && threadIdx.x < 64) Z[threadIdx.x] = 0.0f;
    const long n1 = 6144L * 256;
    const long n2 = 256L * 2048;
    const long stride = (long)gridDim.x * 256;
    for (long i = gid; i < n1; i += stride) w_in_b[i] = __float2bfloat16(w_in[i]);
    for (long i = gid; i < n2; i += stride) w_out_b[i] = __float2bfloat16(w_out[i]);
}

__global__ void prep_xt(const float* __restrict__ x, bf16* __restrict__ x_t)
{
    __shared__ float tile[64][65];
    const int b = blockIdx.x;
    const int n = blockIdx.y;
    const int ct = b & 3, lt = b >> 2;
    const int t = threadIdx.x;
    const float* xp = x + (long)n * 256 * 1024;
#pragma unroll
    for (int i = 0; i < 16; ++i) {
        const int flat = i * 256 + t;
        const int cl = flat >> 6, ll = flat & 63;
        tile[cl][ll] = xp[(long)(ct * 64 + cl) * 1024 + lt * 64 + ll];
    }
    __syncthreads();
    bf16* xo = x_t + (long)n * 1024 * 256;
#pragma unroll
    for (int i = 0; i < 16; ++i) {
        const int flat = i * 256 + t;
        const int lr = flat >> 6, cr = flat & 63;
        xo[(long)(lt * 64 + lr) * 256 + ct * 64 + cr] = __float2bfloat16(tile[cr][lr]);
    }
}

__global__ void prep_v2(const bf16* __restrict__ scaled_t, bf16* __restrict__ v2)
{
    __shared__ bf16 tile[64][74];
    const int b  = blockIdx.x;
    const int nh = blockIdx.y;
    const int dt = b & 3, lt = b >> 2;
    const int n = nh >> 3, h = nh & 7;
    const int t = threadIdx.x;
    const bf16* sp = scaled_t + (long)n * 1024 * 6144 + h * 768 + 512;
#pragma unroll
    for (int i = 0; i < 16; ++i) {
        const int flat = i * 256 + t;
        const int lr = flat >> 6, dc = flat & 63;
        tile[dc][lr] = sp[(long)(lt * 64 + lr) * 6144 + dt * 64 + dc];
    }
    __syncthreads();
    bf16* vp = v2 + ((long)nh * 256 + dt * 64) * 1024;
#pragma unroll
    for (int i = 0; i < 16; ++i) {
        const int flat = i * 256 + t;
        const int dr = flat >> 6, lc = flat & 63;
        vp[(long)dr * 1024 + lt * 64 + lc] = tile[dr][lc];
    }
}

extern "C" void kernel_launch(void* const* d_in, const int* in_sizes, int n_in,
                              void* d_out, int out_size, void* d_ws, size_t ws_size,
                              hipStream_t stream)
{
    const float* x     = (const float*)d_in[0];
    const float* w_in  = (const float*)d_in[1];
    const float* b_in  = (const float*)d_in[2];
    const float* w_out = (const float*)d_in[3];
    const float* b_out = (const float*)d_in[4];
    float* out = (float*)d_out;

    const float SCALE = 0.10416666666666667f;     // 1/16 * sqrt(6400/2304) = 5/48

    char* p = (char*)d_ws;
    bf16* scaled_t = (bf16*)p;  p += 100663296;   // (8, 1024, 6144) bf16
    bf16* v2       = (bf16*)p;  p += 33554432;    // (8, 8, 256, 1024) bf16
    bf16* out_tt   = (bf16*)p;  p += 33554432;    // (8, 1024, 2048) bf16 (unnormalized)
    bf16* x_t      = (bf16*)p;  p += 4194304;     // (8, 1024, 256) bf16
    bf16* w_in_b   = (bf16*)p;  p += 3145728;     // (6144, 256) bf16
    bf16* w_out_b  = (bf16*)p;  p += 1048576;     // (256, 2048) bf16
    float* Z       = (float*)p; p += 256;         // 64 softmax denominators

    prep_convert<<<2048, 256, 0, stream>>>(w_in, w_out, w_in_b, w_out_b, Z);
    prep_xt<<<dim3(64, 8), 256, 0, stream>>>(x, x_t);

    // g1: scaled_t[n,l,o], M=1024(l) N=6144(o) K=256(c)
    gemm_nt<<<dim3(48, 8, 8), 256, 0, stream>>>(
        x_t, w_in_b, scaled_t,
        1024, 6144, 256, 256, 256, 6144,
        1024L * 256, 0, 0, 0, 1024L * 6144, 0,
        1, 0, b_in, nullptr, SCALE);

    prep_v2<<<dim3(64, 64), 256, 0, stream>>>(scaled_t, v2);

    // fused attention (1D grid, XCD-swizzled)
    attn_fused<<<1024, 256, 0, stream>>>(scaled_t, v2, out_tt, Z);

    // g4: out[n,c,m] = w_out . (out_tt/Z) + b_out, M=256(c) N=1024(m) K=2048(a)
    gemm_nt<<<dim3(8, 2, 8), 256, 0, stream>>>(
        w_out_b, out_tt, out,
        256, 1024, 2048, 2048, 2048, 1024,
        0, 0, 1024L * 2048, 0, 256L * 1024, 0,
        1, 4, b_out, Z, 1.0f);
}

// Round 8
// 253.700 us; speedup vs baseline: 1.2585x; 1.2585x over previous
//
#include <hip/hip_runtime.h>
#include <hip/hip_bf16.h>

// MultiHeadAttention: x(8,256,32,32) -> qkv proj -> global-softmax attention -> out proj.
//   g1 (gemm_nt mode 0): scaled_t[n,l,o] = (x_t . w_in + b_in) * SCALE       (K=256)
//   attn_fused:          out_tt[n,m,h*256+d] = Sum_l exp(q_l.k_m) v[d,l]  (UNNORMALIZED)
//                        Z[nh] = Sum exp(q.k)
//   g4 (gemm_nt mode 4): out[n,c,m] = w_out . (out_tt/Z) + b_out
// Global softmax: att ~ N(0,0.17^2) -> exp() without max-subtraction is safe.
// R8: R7's fragment-layout global Q loads were 64-way uncoalesced (64 rows x 12KB apart
//     per instruction) -> VMEM-serialized (MfmaUtil 16%, VALU 10%). Q now staged through
//     a XOR-swizzled LDS tile from COALESCED reads (register prefetch, ds_write at loop
//     bottom); P repacked [kw][m][pad24] so O-phase A-frags are single b128 reads.
//     Keeps R7's 32x32x16 MFMA, K-in-registers, async-LDS V, XCD swizzle.

typedef __bf16 bf16x8 __attribute__((ext_vector_type(8)));
typedef __bf16 bf16x4 __attribute__((ext_vector_type(4)));
typedef float f32x4 __attribute__((ext_vector_type(4)));
typedef float f32x16 __attribute__((ext_vector_type(16)));
typedef __hip_bfloat16 bf16;

__device__ __forceinline__ void async_copy16(const void* g, void* s) {
    __builtin_amdgcn_global_load_lds(
        (const __attribute__((address_space(1))) unsigned int*)g,
        (__attribute__((address_space(3))) unsigned int*)s, 16, 0, 0);
}

__device__ __forceinline__ bf16x8 scale8(bf16x8 v, float s) {
    bf16x8 r;
#pragma unroll
    for (int e = 0; e < 8; ++e) r[e] = (__bf16)((float)v[e] * s);
    return r;
}

// ---------------------------------------------------------------------------
// Generic NT bf16 GEMM, 128x128 tile, BK=64, 256 threads (2x2 waves).
// Register-prefetch pipelined K-loop (R4), XOR-swizzled LDS (R3, 0 conflicts).
// mode 0: C=bf16, (acc + bias[col]) * scale
// mode 3: C=f32,  acc + bias[row]
// mode 4: C=f32,  acc + bias[row]; B scaled by 1/Zp[zn*8 + k/256] during staging
__global__ __launch_bounds__(256)
void gemm_nt(const bf16* __restrict__ A, const bf16* __restrict__ B, void* __restrict__ Cvoid,
             int M, int N, int K, int lda, int ldb, int ldc,
             long asn, long ash, long bsn, long bsh, long csn, long csh,
             int H, int mode, const float* __restrict__ bias, const float* __restrict__ Zp,
             float scale)
{
    __shared__ __align__(16) bf16 smem[17408];
    bf16* Alds = smem;
    bf16* Blds = smem + 8192;

    const int tid  = threadIdx.x;
    const int wave = tid >> 6;
    const int lane = tid & 63;
    const int z  = blockIdx.z;
    const int zn = z / H, zh = z % H;

    const bf16* Ab = A + zn * asn + zh * ash;
    const bf16* Bb = B + zn * bsn + zh * bsh;

    const long tM = (long)blockIdx.y * 128;
    const long tN = (long)blockIdx.x * 128;

    const int wr   = (wave >> 1) * 64;
    const int wc   = (wave & 1) * 64;
    const int l15  = lane & 15;
    const int quad = lane >> 4;

    f32x4 acc[4][4] = {};

    const int kiters = K >> 6;
    const bool regB = (mode == 4);

#pragma unroll
    for (int i = 0; i < 4; ++i) {
        const int flat = i * 256 + tid;
        const int row  = flat >> 3;
        const int kcs  = (flat & 7) ^ (row & 7);
        async_copy16(Ab + (tM + row) * (long)lda + kcs * 8,
                     (char*)Alds + (long)(i * 256 + wave * 64) * 16);
        if (!regB) {
            async_copy16(Bb + (tN + row) * (long)ldb + kcs * 8,
                         (char*)Blds + (long)(i * 256 + wave * 64) * 16);
        }
    }
    if (regB) {
        const float zi0 = 1.0f / Zp[zn * 8];
#pragma unroll
        for (int i = 0; i < 4; ++i) {
            const int flat = i * 256 + tid;
            const int row  = flat >> 3;
            const int kcs  = (flat & 7) ^ (row & 7);
            bf16x8 b = *(const bf16x8*)(Bb + (tN + row) * (long)ldb + kcs * 8);
            *(bf16x8*)((char*)Blds + (long)flat * 16) = scale8(b, zi0);
        }
    }

    bf16x8 pfA[4], pfB[4];
    for (int kt = 0; kt < kiters; ++kt) {
        __syncthreads();
        const bool has_next = (kt + 1 < kiters);
        float zin = 1.0f;
        if (has_next) {
            const long kof = (long)(kt + 1) * 64;
            if (regB) zin = 1.0f / Zp[zn * 8 + ((kt + 1) >> 2)];
#pragma unroll
            for (int i = 0; i < 4; ++i) {
                const int flat = i * 256 + tid;
                const int row  = flat >> 3;
                const int kcs  = (flat & 7) ^ (row & 7);
                pfA[i] = *(const bf16x8*)(Ab + (tM + row) * (long)lda + kof + kcs * 8);
                pfB[i] = *(const bf16x8*)(Bb + (tN + row) * (long)ldb + kof + kcs * 8);
            }
        }
#pragma unroll
        for (int kk = 0; kk < 2; ++kk) {
            bf16x8 af[4], bfv[4];
#pragma unroll
            for (int i = 0; i < 4; ++i) {
                const int r = wr + i * 16 + l15;
                af[i] = *(const bf16x8*)(Alds + r * 64 + ((kk * 4 + quad) ^ (r & 7)) * 8);
            }
#pragma unroll
            for (int j = 0; j < 4; ++j) {
                const int r = wc + j * 16 + l15;
                bfv[j] = *(const bf16x8*)(Blds + r * 64 + ((kk * 4 + quad) ^ (r & 7)) * 8);
            }
#pragma unroll
            for (int i = 0; i < 4; ++i)
#pragma unroll
                for (int j = 0; j < 4; ++j)
                    acc[i][j] = __builtin_amdgcn_mfma_f32_16x16x32_bf16(af[i], bfv[j], acc[i][j], 0, 0, 0);
        }
        if (has_next) {
            __builtin_amdgcn_sched_barrier(0);
            __builtin_amdgcn_s_barrier();
            __builtin_amdgcn_sched_barrier(0);
#pragma unroll
            for (int i = 0; i < 4; ++i) {
                const int flat = i * 256 + tid;
                *(bf16x8*)((char*)Alds + (long)flat * 16) = pfA[i];
                *(bf16x8*)((char*)Blds + (long)flat * 16) = regB ? scale8(pfB[i], zin) : pfB[i];
            }
        }
    }

    if (mode >= 3) {
        float* C = (float*)Cvoid + zn * csn + zh * csh;
#pragma unroll
        for (int i = 0; i < 4; ++i)
#pragma unroll
            for (int j = 0; j < 4; ++j)
#pragma unroll
                for (int r = 0; r < 4; ++r) {
                    const long row = tM + wr + i * 16 + quad * 4 + r;
                    const long col = tN + wc + j * 16 + l15;
                    C[row * (long)ldc + col] = acc[i][j][r] + bias[row];
                }
    } else {
        bf16* Cb = (bf16*)Cvoid + zn * csn + zh * csh + tM * (long)ldc + tN;
        __syncthreads();
#pragma unroll
        for (int i = 0; i < 4; ++i)
#pragma unroll
            for (int j = 0; j < 4; ++j)
#pragma unroll
                for (int r = 0; r < 4; ++r) {
                    const int row = wr + i * 16 + quad * 4 + r;
                    const int col = wc + j * 16 + l15;
                    smem[row * 136 + col] = __float2bfloat16((acc[i][j][r] + bias[col]) * scale);
                }
        __syncthreads();
#pragma unroll
        for (int k = 0; k < 8; ++k) {
            const int fc  = k * 256 + tid;
            const int row = fc >> 4, cc = fc & 15;
            const f32x4 val = *(const f32x4*)((const char*)smem + row * 272 + cc * 16);
            *(f32x4*)((char*)(Cb + (long)row * ldc) + cc * 16) = val;
        }
    }
}

// ---------------------------------------------------------------------------
// Fused attention v4. Block = (64-key m-tile, nh); grid 1024, XCD-swizzled.
// Per l-tile (64 queries):
//   issue async V->Vs and COALESCED Q(lt+1)->regs (both drained at sync1, hidden by S);
//   S: wave (wl,wm) = 32l x 32m; Q b128 from swizzled LDS tile, K resident in 64 VGPRs;
//   exp -> P at [kw][m][pad24] (b64 writes); sync1;
//   O: wave = 64m x 64d-slice; P A-frags single b128, V b128 from swizzled tile;
//   loop bottom: ds_write Q(lt+1) (no barrier needed: nobody reads Qs in O-phase;
//   next B1 makes it visible).
// Fragment layouts (32x32x16): A/B lane holds [row=lane&31][k=(lane>>5)*8+j];
//   C/D: col=lane&31, row=(reg&3)+8*(reg>>2)+4*(lane>>5) (m74/m101, verified R7 pass).
__global__ __launch_bounds__(256, 2)
void attn_fused(const bf16* __restrict__ scaled_t, const bf16* __restrict__ v2,
                bf16* __restrict__ out_tt, float* __restrict__ Z)
{
    __shared__ __align__(16) bf16 smem[30728];
    bf16* Vs = smem;                        // 256d x 64l (linear slots, src-XOR) [0,8192)
    bf16* Qs = smem + 8192;                 // 64l x 256d XOR-swizzled           [8192,24576)
    bf16* Ps = smem + 24576;                // 4kw x 64m x pad24                 [24576,30720)
    float* Zs = (float*)(smem + 30720);     // 4 floats

    const int tid  = threadIdx.x;
    const int wave = tid >> 6, lane = tid & 63;
    const int l31  = lane & 31, hw = lane >> 5;

    const int b   = blockIdx.x;
    const int xcd = b & 7, s = b >> 3;
    const int nh  = xcd * 8 + (s >> 4);     // xcd == n: each XCD streams one batch image
    const int mt_ = s & 15;
    const int n   = nh >> 3, h = nh & 7;
    const long m0 = (long)mt_ * 64;

    const bf16* Qb = scaled_t + (long)n * 6291456 + h * 768;
    const bf16* Kb = Qb + 256;
    const bf16* Vb = v2 + (long)nh * 262144;

    const int wl = wave & 1, wm = wave >> 1;

    // K fragments resident in registers (wave's m-half), reused all 16 iters.
    // One-shot strided load, amortized.
    bf16x8 Kf[16];
    {
        const bf16* Krow = Kb + (m0 + wm * 32 + l31) * 6144;
#pragma unroll
        for (int w = 0; w < 16; ++w)
            Kf[w] = *(const bf16x8*)(Krow + w * 16 + hw * 8);
    }

    // Prologue: coalesced Q(0) -> regs -> swizzled Qs.
    bf16x8 pfQ[8];
#pragma unroll
    for (int i = 0; i < 8; ++i) {
        const int flat = i * 256 + tid;
        const int row  = flat >> 5, ch = flat & 31;
        pfQ[i] = *(const bf16x8*)(Qb + (long)row * 6144 + ch * 8);
    }
#pragma unroll
    for (int i = 0; i < 8; ++i) {
        const int flat = i * 256 + tid;
        const int row  = flat >> 5, ch = flat & 31;
        const int slot = (ch & 24) | ((ch & 7) ^ (row & 7));
        *(bf16x8*)((char*)Qs + row * 512 + slot * 16) = pfQ[i];
    }

    f32x16 accO[2][2] = {};
    float zsum = 0.0f;

    for (int lt = 0; lt < 16; ++lt) {
        const long l0 = (long)lt * 64;
        // B1: Qs(lt) writes visible to all; prev iter's O-phase LDS reads retired.
        // vmem queue empty here (pfQ consumed by bottom ds_write) -> cheap drain.
        __syncthreads();

        // Stage V(lt) via async DMA (drained at sync1, hidden by S-phase).
#pragma unroll
        for (int i = 0; i < 8; ++i) {
            const int flat = i * 256 + tid;
            const int d    = flat >> 3, ch = flat & 7;
            async_copy16(Vb + (long)d * 1024 + l0 + ((ch ^ (d & 7)) * 8),
                         (char*)Vs + (long)(i * 256 + wave * 64) * 16);
        }
        // Issue coalesced Q(lt+1) -> regs (drained at sync1, hidden by S-phase).
        if (lt < 15) {
            const bf16* Qn = Qb + (l0 + 64) * 6144;
#pragma unroll
            for (int i = 0; i < 8; ++i) {
                const int flat = i * 256 + tid;
                const int row  = flat >> 5, ch = flat & 31;
                pfQ[i] = *(const bf16x8*)(Qn + (long)row * 6144 + ch * 8);
            }
        }

        // S-phase: 32l x 32m per wave; Q from LDS, K from registers. Two acc chains.
        f32x16 a0 = {}, a1 = {};
        const int qr = wl * 32 + l31;
#pragma unroll
        for (int w = 0; w < 16; w += 2) {
            const int c0 = 2 * w + hw;
            const int s0 = (c0 & 24) | ((c0 & 7) ^ (qr & 7));
            const bf16x8 q0 = *(const bf16x8*)((char*)Qs + qr * 512 + s0 * 16);
            a0 = __builtin_amdgcn_mfma_f32_32x32x16_bf16(q0, Kf[w], a0, 0, 0, 0);
            const int c1 = 2 * (w + 1) + hw;
            const int s1 = (c1 & 24) | ((c1 & 7) ^ (qr & 7));
            const bf16x8 q1 = *(const bf16x8*)((char*)Qs + qr * 512 + s1 * 16);
            a1 = __builtin_amdgcn_mfma_f32_32x32x16_bf16(q1, Kf[w + 1], a1, 0, 0, 0);
        }

        // exp -> P[kw][m][pad24]; lane's l = wl*32 + 4hw + 8g + e, kw = l>>4, off = l&15.
#pragma unroll
        for (int g = 0; g < 4; ++g) {
            bf16x4 pk;
#pragma unroll
            for (int e = 0; e < 4; ++e) {
                const float v = __expf(a0[g * 4 + e] + a1[g * 4 + e]);
                zsum += v;
                pk[e] = (__bf16)v;
            }
            const int l  = wl * 32 + 4 * hw + 8 * g;
            const int kw = l >> 4, off = l & 15;
            *(bf16x4*)(Ps + kw * 1536 + (wm * 32 + l31) * 24 + off) = pk;
        }

        // sync1: drains async V + pfQ (both hidden by S) and P writes.
        __syncthreads();

        // O-phase: wave = 64m x 64d (d-slice = wave*64), k = 64 over 4 kw windows.
#pragma unroll
        for (int kw = 0; kw < 4; ++kw) {
            bf16x8 pf[2], vf[2];
#pragma unroll
            for (int mt = 0; mt < 2; ++mt)
                pf[mt] = *(const bf16x8*)(Ps + kw * 1536 + (mt * 32 + l31) * 24 + hw * 8);
#pragma unroll
            for (int dt = 0; dt < 2; ++dt) {
                const int d    = wave * 64 + dt * 32 + l31;
                const int slot = (kw * 2 + hw) ^ (d & 7);
                vf[dt] = *(const bf16x8*)(Vs + d * 64 + slot * 8);
            }
#pragma unroll
            for (int mt = 0; mt < 2; ++mt)
#pragma unroll
                for (int dt = 0; dt < 2; ++dt)
                    accO[mt][dt] = __builtin_amdgcn_mfma_f32_32x32x16_bf16(
                        pf[mt], vf[dt], accO[mt][dt], 0, 0, 0);
        }

        // Bottom: stage Q(lt+1). Safe without a barrier: every wave passed sync1
        // (all S-phase Qs reads retired) and nobody reads Qs during O-phase.
        if (lt < 15) {
#pragma unroll
            for (int i = 0; i < 8; ++i) {
                const int flat = i * 256 + tid;
                const int row  = flat >> 5, ch = flat & 31;
                const int slot = (ch & 24) | ((ch & 7) ^ (row & 7));
                *(bf16x8*)((char*)Qs + row * 512 + slot * 16) = pfQ[i];
            }
        }
    }

    __syncthreads();   // final O reads retired; smem becomes the C-stage

    // Z reduction: wave shuffle -> Zs -> one atomicAdd.
#pragma unroll
    for (int o = 32; o > 0; o >>= 1) zsum += __shfl_down(zsum, o);
    if (lane == 0) Zs[wave] = zsum;

    // Stage C (64m x 256d, stride 264) then b128 coalesced stores.
    bf16* Cs = smem;
#pragma unroll
    for (int mt = 0; mt < 2; ++mt)
#pragma unroll
        for (int dt = 0; dt < 2; ++dt)
#pragma unroll
            for (int r = 0; r < 16; ++r) {
                const int m = mt * 32 + (r & 3) + 8 * (r >> 2) + 4 * hw;
                const int d = wave * 64 + dt * 32 + l31;
                Cs[m * 264 + d] = __float2bfloat16(accO[mt][dt][r]);
            }
    __syncthreads();
    if (tid == 0) atomicAdd(Z + nh, (Zs[0] + Zs[1]) + (Zs[2] + Zs[3]));

    bf16* Ob = out_tt + (long)n * 2097152 + m0 * 2048 + h * 256;
#pragma unroll
    for (int k = 0; k < 8; ++k) {
        const int flat = k * 256 + tid;
        const int row  = flat >> 5;
        const int c    = flat & 31;
        const f32x4 val = *(const f32x4*)((const char*)Cs + row * 528 + c * 16);
        *(f32x4*)((char*)(Ob + (long)row * 2048) + c * 16) = val;
    }
}

// ---------------------------------------------------------------------------
__global__ void prep_convert(const float* __restrict__ w_in, const float* __restrict__ w_out,
                             bf16* __restrict__ w_in_b, bf16* __restrict__ w_out_b,
                             float* __restrict__ Z)
{
    const long gid = (long)blockIdx.x * 256 + threadIdx.x;
    if (blockIdx.x == 0 && threadIdx.x < 64) Z[threadIdx.x] = 0.0f;
    const long n1 = 6144L * 256;
    const long n2 = 256L * 2048;
    const long stride = (long)gridDim.x * 256;
    for (long i = gid; i < n1; i += stride) w_in_b[i] = __float2bfloat16(w_in[i]);
    for (long i = gid; i < n2; i += stride) w_out_b[i] = __float2bfloat16(w_out[i]);
}

__global__ void prep_xt(const float* __restrict__ x, bf16* __restrict__ x_t)
{
    __shared__ float tile[64][65];
    const int b = blockIdx.x;
    const int n = blockIdx.y;
    const int ct = b & 3, lt = b >> 2;
    const int t = threadIdx.x;
    const float* xp = x + (long)n * 256 * 1024;
#pragma unroll
    for (int i = 0; i < 16; ++i) {
        const int flat = i * 256 + t;
        const int cl = flat >> 6, ll = flat & 63;
        tile[cl][ll] = xp[(long)(ct * 64 + cl) * 1024 + lt * 64 + ll];
    }
    __syncthreads();
    bf16* xo = x_t + (long)n * 1024 * 256;
#pragma unroll
    for (int i = 0; i < 16; ++i) {
        const int flat = i * 256 + t;
        const int lr = flat >> 6, cr = flat & 63;
        xo[(long)(lt * 64 + lr) * 256 + ct * 64 + cr] = __float2bfloat16(tile[cr][lr]);
    }
}

__global__ void prep_v2(const bf16* __restrict__ scaled_t, bf16* __restrict__ v2)
{
    __shared__ bf16 tile[64][74];
    const int b  = blockIdx.x;
    const int nh = blockIdx.y;
    const int dt = b & 3, lt = b >> 2;
    const int n = nh >> 3, h = nh & 7;
    const int t = threadIdx.x;
    const bf16* sp = scaled_t + (long)n * 1024 * 6144 + h * 768 + 512;
#pragma unroll
    for (int i = 0; i < 16; ++i) {
        const int flat = i * 256 + t;
        const int lr = flat >> 6, dc = flat & 63;
        tile[dc][lr] = sp[(long)(lt * 64 + lr) * 6144 + dt * 64 + dc];
    }
    __syncthreads();
    bf16* vp = v2 + ((long)nh * 256 + dt * 64) * 1024;
#pragma unroll
    for (int i = 0; i < 16; ++i) {
        const int flat = i * 256 + t;
        const int dr = flat >> 6, lc = flat & 63;
        vp[(long)dr * 1024 + lt * 64 + lc] = tile[dr][lc];
    }
}

extern "C" void kernel_launch(void* const* d_in, const int* in_sizes, int n_in,
                              void* d_out, int out_size, void* d_ws, size_t ws_size,
                              hipStream_t stream)
{
    const float* x     = (const float*)d_in[0];
    const float* w_in  = (const float*)d_in[1];
    const float* b_in  = (const float*)d_in[2];
    const float* w_out = (const float*)d_in[3];
    const float* b_out = (const float*)d_in[4];
    float* out = (float*)d_out;

    const float SCALE = 0.10416666666666667f;     // 1/16 * sqrt(6400/2304) = 5/48

    char* p = (char*)d_ws;
    bf16* scaled_t = (bf16*)p;  p += 100663296;   // (8, 1024, 6144) bf16
    bf16* v2       = (bf16*)p;  p += 33554432;    // (8, 8, 256, 1024) bf16
    bf16* out_tt   = (bf16*)p;  p += 33554432;    // (8, 1024, 2048) bf16 (unnormalized)
    bf16* x_t      = (bf16*)p;  p += 4194304;     // (8, 1024, 256) bf16
    bf16* w_in_b   = (bf16*)p;  p += 3145728;     // (6144, 256) bf16
    bf16* w_out_b  = (bf16*)p;  p += 1048576;     // (256, 2048) bf16
    float* Z       = (float*)p; p += 256;         // 64 softmax denominators

    prep_convert<<<2048, 256, 0, stream>>>(w_in, w_out, w_in_b, w_out_b, Z);
    prep_xt<<<dim3(64, 8), 256, 0, stream>>>(x, x_t);

    // g1: scaled_t[n,l,o], M=1024(l) N=6144(o) K=256(c)
    gemm_nt<<<dim3(48, 8, 8), 256, 0, stream>>>(
        x_t, w_in_b, scaled_t,
        1024, 6144, 256, 256, 256, 6144,
        1024L * 256, 0, 0, 0, 1024L * 6144, 0,
        1, 0, b_in, nullptr, SCALE);

    prep_v2<<<dim3(64, 64), 256, 0, stream>>>(scaled_t, v2);

    // fused attention (1D grid, XCD-swizzled)
    attn_fused<<<1024, 256, 0, stream>>>(scaled_t, v2, out_tt, Z);

    // g4: out[n,c,m] = w_out . (out_tt/Z) + b_out, M=256(c) N=1024(m) K=2048(a)
    gemm_nt<<<dim3(8, 2, 8), 256, 0, stream>>>(
        w_out_b, out_tt, out,
        256, 1024, 2048, 2048, 2048, 1024,
        0, 0, 1024L * 2048, 0, 256L * 1024, 0,
        1, 4, b_out, Z, 1.0f);
}

// Round 9
// 245.787 us; speedup vs baseline: 1.2990x; 1.0322x over previous
//
#include <hip/hip_runtime.h>
#include <hip/hip_bf16.h>

// MultiHeadAttention: x(8,256,32,32) -> qkv proj -> global-softmax attention -> out proj.
//   g1 (gemm_nt mode 0): (x_t . w_in + b_in) * SCALE, emitted DIRECTLY into MFMA-fragment-
//                        swizzled buffers Qsw/Ksw/Vsw (routed by blockIdx.x%6; V transposed).
//   attn_fused:          out_tt[n,m,h*256+d] = Sum_l exp(q_l.k_m) v[d,l]  (UNNORMALIZED)
//                        Z[nh] = Sum exp(q.k);  Q/K/V read as coalesced global fragments,
//                        LDS holds ONLY the P tile (12 KB).
//   g4 (gemm_nt mode 4): out[n,c,m] = w_out . (out_tt/Z) + b_out
// Global softmax: att ~ N(0,0.17^2) -> exp() without max-subtraction is safe.
// Fragment layouts (32x32x16, verified working R7/R8): A/B lane: row=lane&31,
//   k=(lane>>5)*8+j; C/D: col=lane&31, row=(reg&3)+8*(reg>>2)+4*(lane>>5).
// Swizzled buffers (bf16):
//   Qsw/Ksw (rows r = l or m, cols d): elem(nh,r,d) at ((nh*32+(r>>5))*16+(d>>4))*512
//        + ((r&31)+32*((d>>3)&1))*8 + (d&7)      -> wave frag = 1024 contiguous bytes.
//   Vsw (rows d, k = l):               elem(nh,l,d) at ((nh*64+(l>>4))*8+(d>>5))*512
//        + ((d&31)+32*((l>>3)&1))*8 + (l&7)
// R9: attn was still LDS-pipe-bound (44 LDS instr/wave-iter ~ 60us/CU). Q/K/V now load
//     as fragments straight from global; LDS = P only. prep_v2/scaled_t deleted.
//     Also fixed: R8's Vs/Qs LDS overlap (race), mode-0 bias local-vs-global index.

typedef __bf16 bf16x8 __attribute__((ext_vector_type(8)));
typedef __bf16 bf16x4 __attribute__((ext_vector_type(4)));
typedef float f32x4 __attribute__((ext_vector_type(4)));
typedef float f32x16 __attribute__((ext_vector_type(16)));
typedef __hip_bfloat16 bf16;

__device__ __forceinline__ void async_copy16(const void* g, void* s) {
    __builtin_amdgcn_global_load_lds(
        (const __attribute__((address_space(1))) unsigned int*)g,
        (__attribute__((address_space(3))) unsigned int*)s, 16, 0, 0);
}

__device__ __forceinline__ bf16x8 scale8(bf16x8 v, float s) {
    bf16x8 r;
#pragma unroll
    for (int e = 0; e < 8; ++e) r[e] = (__bf16)((float)v[e] * s);
    return r;
}

// ---------------------------------------------------------------------------
// Generic NT bf16 GEMM, 128x128 tile, BK=64, 256 threads (2x2 waves).
// Register-prefetch pipelined K-loop (R4), XOR-swizzled LDS (R3, 0 conflicts).
// mode 0: QKV swizzled emit: v=(acc+bias[global col])*scale -> Qsw/Ksw/Vsw by x%6
// mode 3: C=f32, acc + bias[row]
// mode 4: C=f32, acc + bias[row]; B scaled by 1/Zp[zn*8 + k/256] during staging
__global__ __launch_bounds__(256)
void gemm_nt(const bf16* __restrict__ A, const bf16* __restrict__ B, void* __restrict__ Cvoid,
             int M, int N, int K, int lda, int ldb, int ldc,
             long asn, long ash, long bsn, long bsh, long csn, long csh,
             int H, int mode, const float* __restrict__ bias, const float* __restrict__ Zp,
             float scale,
             bf16* __restrict__ outQ, bf16* __restrict__ outK, bf16* __restrict__ outV)
{
    __shared__ __align__(16) bf16 smem[17408];
    bf16* Alds = smem;
    bf16* Blds = smem + 8192;

    const int tid  = threadIdx.x;
    const int wave = tid >> 6;
    const int lane = tid & 63;
    const int z  = blockIdx.z;
    const int zn = z / H, zh = z % H;

    const bf16* Ab = A + zn * asn + zh * ash;
    const bf16* Bb = B + zn * bsn + zh * bsh;

    const long tM = (long)blockIdx.y * 128;
    const long tN = (long)blockIdx.x * 128;

    const int wr   = (wave >> 1) * 64;
    const int wc   = (wave & 1) * 64;
    const int l15  = lane & 15;
    const int quad = lane >> 4;

    f32x4 acc[4][4] = {};

    const int kiters = K >> 6;
    const bool regB = (mode == 4);

#pragma unroll
    for (int i = 0; i < 4; ++i) {
        const int flat = i * 256 + tid;
        const int row  = flat >> 3;
        const int kcs  = (flat & 7) ^ (row & 7);
        async_copy16(Ab + (tM + row) * (long)lda + kcs * 8,
                     (char*)Alds + (long)(i * 256 + wave * 64) * 16);
        if (!regB) {
            async_copy16(Bb + (tN + row) * (long)ldb + kcs * 8,
                         (char*)Blds + (long)(i * 256 + wave * 64) * 16);
        }
    }
    if (regB) {
        const float zi0 = 1.0f / Zp[zn * 8];
#pragma unroll
        for (int i = 0; i < 4; ++i) {
            const int flat = i * 256 + tid;
            const int row  = flat >> 3;
            const int kcs  = (flat & 7) ^ (row & 7);
            bf16x8 b = *(const bf16x8*)(Bb + (tN + row) * (long)ldb + kcs * 8);
            *(bf16x8*)((char*)Blds + (long)flat * 16) = scale8(b, zi0);
        }
    }

    bf16x8 pfA[4], pfB[4];
    for (int kt = 0; kt < kiters; ++kt) {
        __syncthreads();
        const bool has_next = (kt + 1 < kiters);
        float zin = 1.0f;
        if (has_next) {
            const long kof = (long)(kt + 1) * 64;
            if (regB) zin = 1.0f / Zp[zn * 8 + ((kt + 1) >> 2)];
#pragma unroll
            for (int i = 0; i < 4; ++i) {
                const int flat = i * 256 + tid;
                const int row  = flat >> 3;
                const int kcs  = (flat & 7) ^ (row & 7);
                pfA[i] = *(const bf16x8*)(Ab + (tM + row) * (long)lda + kof + kcs * 8);
                pfB[i] = *(const bf16x8*)(Bb + (tN + row) * (long)ldb + kof + kcs * 8);
            }
        }
#pragma unroll
        for (int kk = 0; kk < 2; ++kk) {
            bf16x8 af[4], bfv[4];
#pragma unroll
            for (int i = 0; i < 4; ++i) {
                const int r = wr + i * 16 + l15;
                af[i] = *(const bf16x8*)(Alds + r * 64 + ((kk * 4 + quad) ^ (r & 7)) * 8);
            }
#pragma unroll
            for (int j = 0; j < 4; ++j) {
                const int r = wc + j * 16 + l15;
                bfv[j] = *(const bf16x8*)(Blds + r * 64 + ((kk * 4 + quad) ^ (r & 7)) * 8);
            }
#pragma unroll
            for (int i = 0; i < 4; ++i)
#pragma unroll
                for (int j = 0; j < 4; ++j)
                    acc[i][j] = __builtin_amdgcn_mfma_f32_16x16x32_bf16(af[i], bfv[j], acc[i][j], 0, 0, 0);
        }
        if (has_next) {
            __builtin_amdgcn_sched_barrier(0);
            __builtin_amdgcn_s_barrier();
            __builtin_amdgcn_sched_barrier(0);
#pragma unroll
            for (int i = 0; i < 4; ++i) {
                const int flat = i * 256 + tid;
                *(bf16x8*)((char*)Alds + (long)flat * 16) = pfA[i];
                *(bf16x8*)((char*)Blds + (long)flat * 16) = regB ? scale8(pfB[i], zin) : pfB[i];
            }
        }
    }

    if (mode >= 3) {
        float* C = (float*)Cvoid + zn * csn + zh * csh;
#pragma unroll
        for (int i = 0; i < 4; ++i)
#pragma unroll
            for (int j = 0; j < 4; ++j)
#pragma unroll
                for (int r = 0; r < 4; ++r) {
                    const long row = tM + wr + i * 16 + quad * 4 + r;
                    const long col = tN + wc + j * 16 + l15;
                    C[row * (long)ldc + col] = acc[i][j][r] + bias[row];
                }
        return;
    }

    // mode 0: swizzled QKV emit. Tile x%6: 0,1 -> Q halves; 2,3 -> K; 4,5 -> V.
    const int x    = blockIdx.x;
    const int part = x % 6;
    const int nh   = zn * 8 + x / 6;
    const int d0   = (part & 1) * 128;        // d-offset of this 128-col tile in [0,256)
    const int by   = blockIdx.y;

    __syncthreads();
    if (part < 4) {
        // Stage [row][slot]: slot=(c32&8)|((c32&7)^(row&7)), c32=col>>3. 128x128, 32KB.
#pragma unroll
        for (int i = 0; i < 4; ++i)
#pragma unroll
            for (int j = 0; j < 4; ++j)
#pragma unroll
                for (int r = 0; r < 4; ++r) {
                    const int row = wr + i * 16 + quad * 4 + r;
                    const int col = wc + j * 16 + l15;
                    const float v = (acc[i][j][r] + bias[tN + col]) * scale;
                    const int c32 = col >> 3;
                    const int slot = (c32 & 8) | ((c32 & 7) ^ (row & 7));
                    smem[row * 128 + slot * 8 + (col & 7)] = __float2bfloat16(v);
                }
        __syncthreads();
        bf16* dst = (part < 2) ? outQ : outK;
#pragma unroll
        for (int k = 0; k < 8; ++k) {
            const int flat = k * 256 + tid;
            const int seg  = flat >> 6, ln = flat & 63;
            const int lb   = seg >> 3, wloc = seg & 7;
            const int row  = lb * 32 + (ln & 31);
            const int c32  = wloc * 2 + (ln >> 5);
            const int slot = (c32 & 8) | ((c32 & 7) ^ (row & 7));
            const f32x4 val = *(const f32x4*)(smem + row * 128 + slot * 8);
            const long addr = ((long)(nh * 32 + by * 4 + lb) * 16 + (d0 >> 4) + wloc) * 512 + ln * 8;
            *(f32x4*)(dst + addr) = val;
        }
    } else {
        // V: stage TRANSPOSED [col(d)][slotT]: slotT=(rc&8)|((rc&7)^(col&7)), rc=row>>3.
#pragma unroll
        for (int i = 0; i < 4; ++i)
#pragma unroll
            for (int j = 0; j < 4; ++j)
#pragma unroll
                for (int r = 0; r < 4; ++r) {
                    const int row = wr + i * 16 + quad * 4 + r;     // l
                    const int col = wc + j * 16 + l15;              // d
                    const float v = (acc[i][j][r] + bias[tN + col]) * scale;
                    const int rc = row >> 3;
                    const int slotT = (rc & 8) | ((rc & 7) ^ (col & 7));
                    smem[col * 128 + slotT * 8 + (row & 7)] = __float2bfloat16(v);
                }
        __syncthreads();
#pragma unroll
        for (int k = 0; k < 8; ++k) {
            const int flat = k * 256 + tid;
            const int seg  = flat >> 6, ln = flat & 63;
            const int kwl  = seg >> 2, g2l = seg & 3;
            const int dl   = g2l * 32 + (ln & 31);
            const int lc   = kwl * 2 + (ln >> 5);
            const int slotT = (lc & 8) | ((lc & 7) ^ (dl & 7));
            const f32x4 val = *(const f32x4*)(smem + dl * 128 + slotT * 8);
            const long addr = ((long)(nh * 64 + by * 8 + kwl) * 8 + (d0 >> 5) + g2l) * 512 + ln * 8;
            *(f32x4*)(outV + addr) = val;
        }
    }
}

// ---------------------------------------------------------------------------
// Fused attention v5. Block = (64-key m-tile, nh); grid 1024, XCD-swizzled.
// Q/K/V load as coalesced global FRAGMENTS (1024B/wave-instr) from Qsw/Ksw/Vsw.
// LDS = P tile only. Per l-tile: issue V frags -> regs; S = Q.K^T (Q global, K
// resident 64 VGPRs); exp -> P (LDS); sync; O += P.V^T; sync.
__global__ __launch_bounds__(256, 2)
void attn_fused(const bf16* __restrict__ Qsw, const bf16* __restrict__ Ksw,
                const bf16* __restrict__ Vsw, bf16* __restrict__ out_tt,
                float* __restrict__ Z)
{
    __shared__ __align__(16) bf16 smem[16904];
    bf16* Ps  = smem;                     // [kw4][m64][pad24] = 6144 elems (in-loop)
    float* Zs = (float*)(smem + 16896);   // epilogue C-stage reuses smem[0..16896)

    const int tid  = threadIdx.x;
    const int wave = tid >> 6, lane = tid & 63;
    const int l31  = lane & 31, hw = lane >> 5;

    const int b   = blockIdx.x;
    const int xcd = b & 7, s = b >> 3;
    const int nh  = xcd * 8 + (s >> 4);   // xcd == n: each XCD streams one batch image
    const int mt  = s & 15;
    const int n   = nh >> 3, h = nh & 7;
    const long m0 = (long)mt * 64;

    const int wl = wave & 1, wm = wave >> 1;

    // K fragments resident (wave's m-half), coalesced load from Ksw, reused 16 iters.
    bf16x8 Kf[16];
    {
        const bf16* kb = Ksw + ((long)(nh * 32 + mt * 2 + wm) * 16) * 512 + lane * 8;
#pragma unroll
        for (int w = 0; w < 16; ++w)
            Kf[w] = *(const bf16x8*)(kb + w * 512);
    }

    f32x16 accO[2][2] = {};
    float zsum = 0.0f;

    for (int lt = 0; lt < 16; ++lt) {
        // Issue V fragments for this l-tile (consumed after sync1; hidden by S-phase).
        bf16x8 vf[4][2];
#pragma unroll
        for (int kw = 0; kw < 4; ++kw)
#pragma unroll
            for (int dt = 0; dt < 2; ++dt)
                vf[kw][dt] = *(const bf16x8*)(
                    Vsw + ((long)(nh * 64 + lt * 4 + kw) * 8 + wave * 2 + dt) * 512 + lane * 8);

        // S-phase: 32l x 32m per wave; Q fragments direct from global (coalesced).
        const bf16* qb = Qsw + ((long)(nh * 32 + lt * 2 + wl) * 16) * 512 + lane * 8;
        f32x16 a0 = {}, a1 = {};
#pragma unroll
        for (int w = 0; w < 16; w += 2) {
            const bf16x8 q0 = *(const bf16x8*)(qb + w * 512);
            a0 = __builtin_amdgcn_mfma_f32_32x32x16_bf16(q0, Kf[w], a0, 0, 0, 0);
            const bf16x8 q1 = *(const bf16x8*)(qb + (w + 1) * 512);
            a1 = __builtin_amdgcn_mfma_f32_32x32x16_bf16(q1, Kf[w + 1], a1, 0, 0, 0);
        }

        // exp -> P[kw][m][pad24]; lane's l = wl*32 + 4hw + 8g + e.
#pragma unroll
        for (int g = 0; g < 4; ++g) {
            bf16x4 pk;
#pragma unroll
            for (int e = 0; e < 4; ++e) {
                const float v = __expf(a0[g * 4 + e] + a1[g * 4 + e]);
                zsum += v;
                pk[e] = (__bf16)v;
            }
            const int l  = wl * 32 + 4 * hw + 8 * g;
            const int kw = l >> 4, off = l & 15;
            *(bf16x4*)(Ps + kw * 1536 + (wm * 32 + l31) * 24 + off) = pk;
        }

        __syncthreads();   // P visible to all waves (vmem queue ~empty: loads consumed)

        // O-phase: wave = 64m x 64d (d-slice = wave*64), k = 64 over 4 kw windows.
#pragma unroll
        for (int kw = 0; kw < 4; ++kw) {
            bf16x8 pf[2];
#pragma unroll
            for (int mh = 0; mh < 2; ++mh)
                pf[mh] = *(const bf16x8*)(Ps + kw * 1536 + (mh * 32 + l31) * 24 + hw * 8);
#pragma unroll
            for (int mh = 0; mh < 2; ++mh)
#pragma unroll
                for (int dt = 0; dt < 2; ++dt)
                    accO[mh][dt] = __builtin_amdgcn_mfma_f32_32x32x16_bf16(
                        pf[mh], vf[kw][dt], accO[mh][dt], 0, 0, 0);
        }
        __syncthreads();   // P reads retired before next iter's writes
    }

    // Z reduction: wave shuffle -> Zs -> one atomicAdd per block.
#pragma unroll
    for (int o = 32; o > 0; o >>= 1) zsum += __shfl_down(zsum, o);
    if (lane == 0) Zs[wave] = zsum;

    // Epilogue: stage 64m x 256d (stride 264) then b128 coalesced stores.
    bf16* Cs = smem;
#pragma unroll
    for (int mh = 0; mh < 2; ++mh)
#pragma unroll
        for (int dt = 0; dt < 2; ++dt)
#pragma unroll
            for (int r = 0; r < 16; ++r) {
                const int m = mh * 32 + (r & 3) + 8 * (r >> 2) + 4 * hw;
                const int d = wave * 64 + dt * 32 + l31;
                Cs[m * 264 + d] = __float2bfloat16(accO[mh][dt][r]);
            }
    __syncthreads();
    if (tid == 0) atomicAdd(Z + nh, (Zs[0] + Zs[1]) + (Zs[2] + Zs[3]));

    bf16* Ob = out_tt + (long)n * 2097152 + m0 * 2048 + h * 256;
#pragma unroll
    for (int k = 0; k < 8; ++k) {
        const int flat = k * 256 + tid;
        const int row  = flat >> 5;
        const int c    = flat & 31;
        const f32x4 val = *(const f32x4*)((const char*)Cs + row * 528 + c * 16);
        *(f32x4*)((char*)(Ob + (long)row * 2048) + c * 16) = val;
    }
}

// ---------------------------------------------------------------------------
__global__ void prep_convert(const float* __restrict__ w_in, const float* __restrict__ w_out,
                             bf16* __restrict__ w_in_b, bf16* __restrict__ w_out_b,
                             float* __restrict__ Z)
{
    const long gid = (long)blockIdx.x * 256 + threadIdx.x;
    if (blockIdx.x == 0 && threadIdx.x < 64) Z[threadIdx.x] = 0.0f;
    const long n1 = 6144L * 256;
    const long n2 = 256L * 2048;
    const long stride = (long)gridDim.x * 256;
    for (long i = gid; i < n1; i += stride) w_in_b[i] = __float2bfloat16(w_in[i]);
    for (long i = gid; i < n2; i += stride) w_out_b[i] = __float2bfloat16(w_out[i]);
}

__global__ void prep_xt(const float* __restrict__ x, bf16* __restrict__ x_t)
{
    __shared__ float tile[64][65];
    const int b = blockIdx.x;
    const int n = blockIdx.y;
    const int ct = b & 3, lt = b >> 2;
    const int t = threadIdx.x;
    const float* xp = x + (long)n * 256 * 1024;
#pragma unroll
    for (int i = 0; i < 16; ++i) {
        const int flat = i * 256 + t;
        const int cl = flat >> 6, ll = flat & 63;
        tile[cl][ll] = xp[(long)(ct * 64 + cl) * 1024 + lt * 64 + ll];
    }
    __syncthreads();
    bf16* xo = x_t + (long)n * 1024 * 256;
#pragma unroll
    for (int i = 0; i < 16; ++i) {
        const int flat = i * 256 + t;
        const int lr = flat >> 6, cr = flat & 63;
        xo[(long)(lt * 64 + lr) * 256 + ct * 64 + cr] = __float2bfloat16(tile[cr][lr]);
    }
}

extern "C" void kernel_launch(void* const* d_in, const int* in_sizes, int n_in,
                              void* d_out, int out_size, void* d_ws, size_t ws_size,
                              hipStream_t stream)
{
    const float* x     = (const float*)d_in[0];
    const float* w_in  = (const float*)d_in[1];
    const float* b_in  = (const float*)d_in[2];
    const float* w_out = (const float*)d_in[3];
    const float* b_out = (const float*)d_in[4];
    float* out = (float*)d_out;

    const float SCALE = 0.10416666666666667f;     // 1/16 * sqrt(6400/2304) = 5/48

    char* p = (char*)d_ws;
    bf16* Qsw     = (bf16*)p;  p += 33554432;     // 64nh x 32lb x 16w x 512 bf16
    bf16* Ksw     = (bf16*)p;  p += 33554432;     // same layout, rows = m
    bf16* Vsw     = (bf16*)p;  p += 33554432;     // 64nh x 64kw x 8g2 x 512 bf16
    bf16* out_tt  = (bf16*)p;  p += 33554432;     // (8, 1024, 2048) bf16 (unnormalized)
    bf16* x_t     = (bf16*)p;  p += 4194304;      // (8, 1024, 256) bf16
    bf16* w_in_b  = (bf16*)p;  p += 3145728;      // (6144, 256) bf16
    bf16* w_out_b = (bf16*)p;  p += 1048576;      // (256, 2048) bf16
    float* Z      = (float*)p; p += 256;          // 64 softmax denominators

    prep_convert<<<2048, 256, 0, stream>>>(w_in, w_out, w_in_b, w_out_b, Z);
    prep_xt<<<dim3(64, 8), 256, 0, stream>>>(x, x_t);

    // g1: M=1024(l) N=6144(o) K=256(c); epilogue emits Qsw/Ksw/Vsw directly.
    gemm_nt<<<dim3(48, 8, 8), 256, 0, stream>>>(
        x_t, w_in_b, nullptr,
        1024, 6144, 256, 256, 256, 0,
        1024L * 256, 0, 0, 0, 0, 0,
        1, 0, b_in, nullptr, SCALE, Qsw, Ksw, Vsw);

    // fused attention (1D grid, XCD-swizzled)
    attn_fused<<<1024, 256, 0, stream>>>(Qsw, Ksw, Vsw, out_tt, Z);

    // g4: out[n,c,m] = w_out . (out_tt/Z) + b_out, M=256(c) N=1024(m) K=2048(a)
    gemm_nt<<<dim3(8, 2, 8), 256, 0, stream>>>(
        w_out_b, out_tt, out,
        256, 1024, 2048, 2048, 2048, 1024,
        0, 0, 1024L * 2048, 0, 256L * 1024, 0,
        1, 4, b_out, Z, 1.0f, nullptr, nullptr, nullptr);
}

// Round 10
// 234.253 us; speedup vs baseline: 1.3629x; 1.0492x over previous
//
#include <hip/hip_runtime.h>
#include <hip/hip_bf16.h>

// MultiHeadAttention: x(8,256,32,32) -> qkv proj -> global-softmax attention -> out proj.
//   g1 (gemm_nt mode 0): (x_t . w_in + b_in) * SCALE, emitted DIRECTLY into MFMA-fragment-
//                        swizzled buffers Qsw/Ksw/Vsw (routed by blockIdx.x%6; V transposed).
//   attn_fused:          out_tt[n,m,h*256+d] = Sum_l exp(q_l.k_m) v[d,l]  (UNNORMALIZED)
//                        Z[nh] = Sum exp(q.k);  Q/K/V read as coalesced global fragments.
//   g4 (gemm_nt mode 4): out[n,c,m] = w_out . (out_tt/Z) + b_out, split-K=2 atomic.
// Global softmax: att ~ N(0,0.17^2) -> exp() without max-subtraction is safe.
// R10: attn was latency-bound at barriers (R9: MfmaUtil 28 + VALU 16, HBM 10 — nothing
//      saturated). P double-buffered -> ONE barrier/iter; Q prefetched IN-PLACE during
//      the O-phase (waitcnt lands at next S, covered by O; never drained by a barrier).
//      g4 was 0.5 blocks/CU -> split-K=2 with atomicAdd epilogue (out zeroed in prep).

typedef __bf16 bf16x8 __attribute__((ext_vector_type(8)));
typedef __bf16 bf16x4 __attribute__((ext_vector_type(4)));
typedef float f32x4 __attribute__((ext_vector_type(4)));
typedef float f32x16 __attribute__((ext_vector_type(16)));
typedef __hip_bfloat16 bf16;

__device__ __forceinline__ void async_copy16(const void* g, void* s) {
    __builtin_amdgcn_global_load_lds(
        (const __attribute__((address_space(1))) unsigned int*)g,
        (__attribute__((address_space(3))) unsigned int*)s, 16, 0, 0);
}

__device__ __forceinline__ bf16x8 scale8(bf16x8 v, float s) {
    bf16x8 r;
#pragma unroll
    for (int e = 0; e < 8; ++e) r[e] = (__bf16)((float)v[e] * s);
    return r;
}

// ---------------------------------------------------------------------------
// Generic NT bf16 GEMM, 128x128 tile, BK=64, 256 threads (2x2 waves).
// Register-prefetch pipelined K-loop (R4), XOR-swizzled LDS (R3, 0 conflicts).
// mode 0: QKV swizzled emit: v=(acc+bias[global col])*scale -> Qsw/Ksw/Vsw by x%6
// mode 3: C=f32, acc + bias[row]
// mode 4: split-K atomic: atomicAdd(C, acc + (zh==0 ? bias[row] : 0));
//         B scaled by 1/Zp[zn*8 + zh*4 + k/256] during staging (H=2, K=1024/chunk)
__global__ __launch_bounds__(256)
void gemm_nt(const bf16* __restrict__ A, const bf16* __restrict__ B, void* __restrict__ Cvoid,
             int M, int N, int K, int lda, int ldb, int ldc,
             long asn, long ash, long bsn, long bsh, long csn, long csh,
             int H, int mode, const float* __restrict__ bias, const float* __restrict__ Zp,
             float scale,
             bf16* __restrict__ outQ, bf16* __restrict__ outK, bf16* __restrict__ outV)
{
    __shared__ __align__(16) bf16 smem[17408];
    bf16* Alds = smem;
    bf16* Blds = smem + 8192;

    const int tid  = threadIdx.x;
    const int wave = tid >> 6;
    const int lane = tid & 63;
    const int z  = blockIdx.z;
    const int zn = z / H, zh = z % H;

    const bf16* Ab = A + zn * asn + zh * ash;
    const bf16* Bb = B + zn * bsn + zh * bsh;

    const long tM = (long)blockIdx.y * 128;
    const long tN = (long)blockIdx.x * 128;

    const int wr   = (wave >> 1) * 64;
    const int wc   = (wave & 1) * 64;
    const int l15  = lane & 15;
    const int quad = lane >> 4;

    f32x4 acc[4][4] = {};

    const int kiters = K >> 6;
    const bool regB = (mode == 4);

#pragma unroll
    for (int i = 0; i < 4; ++i) {
        const int flat = i * 256 + tid;
        const int row  = flat >> 3;
        const int kcs  = (flat & 7) ^ (row & 7);
        async_copy16(Ab + (tM + row) * (long)lda + kcs * 8,
                     (char*)Alds + (long)(i * 256 + wave * 64) * 16);
        if (!regB) {
            async_copy16(Bb + (tN + row) * (long)ldb + kcs * 8,
                         (char*)Blds + (long)(i * 256 + wave * 64) * 16);
        }
    }
    if (regB) {
        const float zi0 = 1.0f / Zp[zn * 8 + zh * 4];
#pragma unroll
        for (int i = 0; i < 4; ++i) {
            const int flat = i * 256 + tid;
            const int row  = flat >> 3;
            const int kcs  = (flat & 7) ^ (row & 7);
            bf16x8 b = *(const bf16x8*)(Bb + (tN + row) * (long)ldb + kcs * 8);
            *(bf16x8*)((char*)Blds + (long)flat * 16) = scale8(b, zi0);
        }
    }

    bf16x8 pfA[4], pfB[4];
    for (int kt = 0; kt < kiters; ++kt) {
        __syncthreads();
        const bool has_next = (kt + 1 < kiters);
        float zin = 1.0f;
        if (has_next) {
            const long kof = (long)(kt + 1) * 64;
            if (regB) zin = 1.0f / Zp[zn * 8 + zh * 4 + ((kt + 1) >> 2)];
#pragma unroll
            for (int i = 0; i < 4; ++i) {
                const int flat = i * 256 + tid;
                const int row  = flat >> 3;
                const int kcs  = (flat & 7) ^ (row & 7);
                pfA[i] = *(const bf16x8*)(Ab + (tM + row) * (long)lda + kof + kcs * 8);
                pfB[i] = *(const bf16x8*)(Bb + (tN + row) * (long)ldb + kof + kcs * 8);
            }
        }
#pragma unroll
        for (int kk = 0; kk < 2; ++kk) {
            bf16x8 af[4], bfv[4];
#pragma unroll
            for (int i = 0; i < 4; ++i) {
                const int r = wr + i * 16 + l15;
                af[i] = *(const bf16x8*)(Alds + r * 64 + ((kk * 4 + quad) ^ (r & 7)) * 8);
            }
#pragma unroll
            for (int j = 0; j < 4; ++j) {
                const int r = wc + j * 16 + l15;
                bfv[j] = *(const bf16x8*)(Blds + r * 64 + ((kk * 4 + quad) ^ (r & 7)) * 8);
            }
#pragma unroll
            for (int i = 0; i < 4; ++i)
#pragma unroll
                for (int j = 0; j < 4; ++j)
                    acc[i][j] = __builtin_amdgcn_mfma_f32_16x16x32_bf16(af[i], bfv[j], acc[i][j], 0, 0, 0);
        }
        if (has_next) {
            __builtin_amdgcn_sched_barrier(0);
            __builtin_amdgcn_s_barrier();
            __builtin_amdgcn_sched_barrier(0);
#pragma unroll
            for (int i = 0; i < 4; ++i) {
                const int flat = i * 256 + tid;
                *(bf16x8*)((char*)Alds + (long)flat * 16) = pfA[i];
                *(bf16x8*)((char*)Blds + (long)flat * 16) = regB ? scale8(pfB[i], zin) : pfB[i];
            }
        }
    }

    if (mode >= 3) {
        float* C = (float*)Cvoid + zn * csn + zh * csh;
#pragma unroll
        for (int i = 0; i < 4; ++i)
#pragma unroll
            for (int j = 0; j < 4; ++j)
#pragma unroll
                for (int r = 0; r < 4; ++r) {
                    const long row = tM + wr + i * 16 + quad * 4 + r;
                    const long col = tN + wc + j * 16 + l15;
                    if (mode == 4) {
                        const float v = acc[i][j][r] + (zh == 0 ? bias[row] : 0.0f);
                        atomicAdd(&C[row * (long)ldc + col], v);
                    } else {
                        C[row * (long)ldc + col] = acc[i][j][r] + bias[row];
                    }
                }
        return;
    }

    // mode 0: swizzled QKV emit. Tile x%6: 0,1 -> Q halves; 2,3 -> K; 4,5 -> V.
    const int x    = blockIdx.x;
    const int part = x % 6;
    const int nh   = zn * 8 + x / 6;
    const int d0   = (part & 1) * 128;
    const int by   = blockIdx.y;

    __syncthreads();
    if (part < 4) {
#pragma unroll
        for (int i = 0; i < 4; ++i)
#pragma unroll
            for (int j = 0; j < 4; ++j)
#pragma unroll
                for (int r = 0; r < 4; ++r) {
                    const int row = wr + i * 16 + quad * 4 + r;
                    const int col = wc + j * 16 + l15;
                    const float v = (acc[i][j][r] + bias[tN + col]) * scale;
                    const int c32 = col >> 3;
                    const int slot = (c32 & 8) | ((c32 & 7) ^ (row & 7));
                    smem[row * 128 + slot * 8 + (col & 7)] = __float2bfloat16(v);
                }
        __syncthreads();
        bf16* dst = (part < 2) ? outQ : outK;
#pragma unroll
        for (int k = 0; k < 8; ++k) {
            const int flat = k * 256 + tid;
            const int seg  = flat >> 6, ln = flat & 63;
            const int lb   = seg >> 3, wloc = seg & 7;
            const int row  = lb * 32 + (ln & 31);
            const int c32  = wloc * 2 + (ln >> 5);
            const int slot = (c32 & 8) | ((c32 & 7) ^ (row & 7));
            const f32x4 val = *(const f32x4*)(smem + row * 128 + slot * 8);
            const long addr = ((long)(nh * 32 + by * 4 + lb) * 16 + (d0 >> 4) + wloc) * 512 + ln * 8;
            *(f32x4*)(dst + addr) = val;
        }
    } else {
#pragma unroll
        for (int i = 0; i < 4; ++i)
#pragma unroll
            for (int j = 0; j < 4; ++j)
#pragma unroll
                for (int r = 0; r < 4; ++r) {
                    const int row = wr + i * 16 + quad * 4 + r;     // l
                    const int col = wc + j * 16 + l15;              // d
                    const float v = (acc[i][j][r] + bias[tN + col]) * scale;
                    const int rc = row >> 3;
                    const int slotT = (rc & 8) | ((rc & 7) ^ (col & 7));
                    smem[col * 128 + slotT * 8 + (row & 7)] = __float2bfloat16(v);
                }
        __syncthreads();
#pragma unroll
        for (int k = 0; k < 8; ++k) {
            const int flat = k * 256 + tid;
            const int seg  = flat >> 6, ln = flat & 63;
            const int kwl  = seg >> 2, g2l = seg & 3;
            const int dl   = g2l * 32 + (ln & 31);
            const int lc   = kwl * 2 + (ln >> 5);
            const int slotT = (lc & 8) | ((lc & 7) ^ (dl & 7));
            const f32x4 val = *(const f32x4*)(smem + dl * 128 + slotT * 8);
            const long addr = ((long)(nh * 64 + by * 8 + kwl) * 8 + (d0 >> 5) + g2l) * 512 + ln * 8;
            *(f32x4*)(outV + addr) = val;
        }
    }
}

// ---------------------------------------------------------------------------
// Fused attention v6. Block = (64-key m-tile, nh); grid 1024, XCD-swizzled.
// Q/K/V as coalesced global fragments; LDS = double-buffered P only.
// Per iter: issue V->regs; S = Q.K^T (Q regs prefetched last iter, K resident);
// exp -> Ps[lt&1]; ONE barrier; O-phase (+ in-place Qc prefetch for lt+1).
__global__ __launch_bounds__(256, 2)
void attn_fused(const bf16* __restrict__ Qsw, const bf16* __restrict__ Ksw,
                const bf16* __restrict__ Vsw, bf16* __restrict__ out_tt,
                float* __restrict__ Z)
{
    __shared__ __align__(16) bf16 smem[16904];
    bf16* Ps  = smem;                     // [2][kw4][m64][pad24] = 12288 elems (in-loop)
    float* Zs = (float*)(smem + 16896);   // epilogue C-stage reuses smem[0..16896)

    const int tid  = threadIdx.x;
    const int wave = tid >> 6, lane = tid & 63;
    const int l31  = lane & 31, hw = lane >> 5;

    const int b   = blockIdx.x;
    const int xcd = b & 7, s = b >> 3;
    const int nh  = xcd * 8 + (s >> 4);   // xcd == n: each XCD streams one batch image
    const int mt  = s & 15;
    const int n   = nh >> 3, h = nh & 7;
    const long m0 = (long)mt * 64;

    const int wl = wave & 1, wm = wave >> 1;

    // K fragments resident (wave's m-half), coalesced, reused 16 iters.
    bf16x8 Kf[16];
    {
        const bf16* kb = Ksw + ((long)(nh * 32 + mt * 2 + wm) * 16) * 512 + lane * 8;
#pragma unroll
        for (int w = 0; w < 16; ++w)
            Kf[w] = *(const bf16x8*)(kb + w * 512);
    }
    // Q(0) fragments.
    bf16x8 Qc[16];
    {
        const bf16* qb = Qsw + ((long)(nh * 32 + wl) * 16) * 512 + lane * 8;
#pragma unroll
        for (int w = 0; w < 16; ++w)
            Qc[w] = *(const bf16x8*)(qb + w * 512);
    }

    f32x16 accO[2][2] = {};
    float zsum = 0.0f;

    for (int lt = 0; lt < 16; ++lt) {
        // V fragments (consumed in O-phase; latency hidden by S).
        bf16x8 vf[4][2];
#pragma unroll
        for (int kw = 0; kw < 4; ++kw)
#pragma unroll
            for (int dt = 0; dt < 2; ++dt)
                vf[kw][dt] = *(const bf16x8*)(
                    Vsw + ((long)(nh * 64 + lt * 4 + kw) * 8 + wave * 2 + dt) * 512 + lane * 8);

        // S-phase: 32l x 32m per wave from registers (Qc prefetched in prev O-phase).
        f32x16 a0 = {}, a1 = {};
#pragma unroll
        for (int w = 0; w < 16; w += 2) {
            a0 = __builtin_amdgcn_mfma_f32_32x32x16_bf16(Qc[w], Kf[w], a0, 0, 0, 0);
            a1 = __builtin_amdgcn_mfma_f32_32x32x16_bf16(Qc[w + 1], Kf[w + 1], a1, 0, 0, 0);
        }

        // exp -> Ps[lt&1]; lane's l = wl*32 + 4hw + 8g + e.
        bf16* Pb = Ps + (lt & 1) * 6144;
#pragma unroll
        for (int g = 0; g < 4; ++g) {
            bf16x4 pk;
#pragma unroll
            for (int e = 0; e < 4; ++e) {
                const float v = __expf(a0[g * 4 + e] + a1[g * 4 + e]);
                zsum += v;
                pk[e] = (__bf16)v;
            }
            const int l  = wl * 32 + 4 * hw + 8 * g;
            const int kw = l >> 4, off = l & 15;
            *(bf16x4*)(Pb + kw * 1536 + (wm * 32 + l31) * 24 + off) = pk;
        }

        // ONE barrier per iter: P(lt) visible; prev O-phase reads of Ps[(lt-1)&1]
        // are ordered by the PREVIOUS barrier + dbuf (waves stay within 1 iter).
        __syncthreads();

        // In-place Qc prefetch for lt+1 (Qc dead after S). waitcnt lands at next S,
        // covered by the O-phase; no barrier between issue and use.
        if (lt < 15) {
            const bf16* qn = Qsw + ((long)(nh * 32 + (lt + 1) * 2 + wl) * 16) * 512 + lane * 8;
#pragma unroll
            for (int w = 0; w < 16; ++w)
                Qc[w] = *(const bf16x8*)(qn + w * 512);
        }

        // O-phase: wave = 64m x 64d (d-slice = wave*64), k = 64 over 4 kw windows.
#pragma unroll
        for (int kw = 0; kw < 4; ++kw) {
            bf16x8 pf[2];
#pragma unroll
            for (int mh = 0; mh < 2; ++mh)
                pf[mh] = *(const bf16x8*)(Pb + kw * 1536 + (mh * 32 + l31) * 24 + hw * 8);
#pragma unroll
            for (int mh = 0; mh < 2; ++mh)
#pragma unroll
                for (int dt = 0; dt < 2; ++dt)
                    accO[mh][dt] = __builtin_amdgcn_mfma_f32_32x32x16_bf16(
                        pf[mh], vf[kw][dt], accO[mh][dt], 0, 0, 0);
        }
    }

    __syncthreads();   // final O reads retired; smem becomes the C-stage

    // Z reduction: wave shuffle -> Zs -> one atomicAdd per block.
#pragma unroll
    for (int o = 32; o > 0; o >>= 1) zsum += __shfl_down(zsum, o);
    if (lane == 0) Zs[wave] = zsum;

    // Epilogue: stage 64m x 256d (stride 264) then b128 coalesced stores.
    bf16* Cs = smem;
#pragma unroll
    for (int mh = 0; mh < 2; ++mh)
#pragma unroll
        for (int dt = 0; dt < 2; ++dt)
#pragma unroll
            for (int r = 0; r < 16; ++r) {
                const int m = mh * 32 + (r & 3) + 8 * (r >> 2) + 4 * hw;
                const int d = wave * 64 + dt * 32 + l31;
                Cs[m * 264 + d] = __float2bfloat16(accO[mh][dt][r]);
            }
    __syncthreads();
    if (tid == 0) atomicAdd(Z + nh, (Zs[0] + Zs[1]) + (Zs[2] + Zs[3]));

    bf16* Ob = out_tt + (long)n * 2097152 + m0 * 2048 + h * 256;
#pragma unroll
    for (int k = 0; k < 8; ++k) {
        const int flat = k * 256 + tid;
        const int row  = flat >> 5;
        const int c    = flat & 31;
        const f32x4 val = *(const f32x4*)((const char*)Cs + row * 528 + c * 16);
        *(f32x4*)((char*)(Ob + (long)row * 2048) + c * 16) = val;
    }
}

// ---------------------------------------------------------------------------
// Convert weights to bf16; zero Z and d_out (for g4's split-K atomics).
__global__ void prep_convert(const float* __restrict__ w_in, const float* __restrict__ w_out,
                             bf16* __restrict__ w_in_b, bf16* __restrict__ w_out_b,
                             float* __restrict__ Z, float* __restrict__ out)
{
    const long gid = (long)blockIdx.x * 256 + threadIdx.x;
    if (blockIdx.x == 0 && threadIdx.x < 64) Z[threadIdx.x] = 0.0f;
    // zero d_out: 2097152 floats = 524288 float4 = exactly one per thread (2048x256)
    const f32x4 z4 = {0.0f, 0.0f, 0.0f, 0.0f};
    if (gid < 524288) ((f32x4*)out)[gid] = z4;
    const long n1 = 6144L * 256;
    const long n2 = 256L * 2048;
    const long stride = (long)gridDim.x * 256;
    for (long i = gid; i < n1; i += stride) w_in_b[i] = __float2bfloat16(w_in[i]);
    for (long i = gid; i < n2; i += stride) w_out_b[i] = __float2bfloat16(w_out[i]);
}

__global__ void prep_xt(const float* __restrict__ x, bf16* __restrict__ x_t)
{
    __shared__ float tile[64][65];
    const int b = blockIdx.x;
    const int n = blockIdx.y;
    const int ct = b & 3, lt = b >> 2;
    const int t = threadIdx.x;
    const float* xp = x + (long)n * 256 * 1024;
#pragma unroll
    for (int i = 0; i < 16; ++i) {
        const int flat = i * 256 + t;
        const int cl = flat >> 6, ll = flat & 63;
        tile[cl][ll] = xp[(long)(ct * 64 + cl) * 1024 + lt * 64 + ll];
    }
    __syncthreads();
    bf16* xo = x_t + (long)n * 1024 * 256;
#pragma unroll
    for (int i = 0; i < 16; ++i) {
        const int flat = i * 256 + t;
        const int lr = flat >> 6, cr = flat & 63;
        xo[(long)(lt * 64 + lr) * 256 + ct * 64 + cr] = __float2bfloat16(tile[cr][lr]);
    }
}

extern "C" void kernel_launch(void* const* d_in, const int* in_sizes, int n_in,
                              void* d_out, int out_size, void* d_ws, size_t ws_size,
                              hipStream_t stream)
{
    const float* x     = (const float*)d_in[0];
    const float* w_in  = (const float*)d_in[1];
    const float* b_in  = (const float*)d_in[2];
    const float* w_out = (const float*)d_in[3];
    const float* b_out = (const float*)d_in[4];
    float* out = (float*)d_out;

    const float SCALE = 0.10416666666666667f;     // 1/16 * sqrt(6400/2304) = 5/48

    char* p = (char*)d_ws;
    bf16* Qsw     = (bf16*)p;  p += 33554432;     // 64nh x 32lb x 16w x 512 bf16
    bf16* Ksw     = (bf16*)p;  p += 33554432;     // same layout, rows = m
    bf16* Vsw     = (bf16*)p;  p += 33554432;     // 64nh x 64kw x 8g2 x 512 bf16
    bf16* out_tt  = (bf16*)p;  p += 33554432;     // (8, 1024, 2048) bf16 (unnormalized)
    bf16* x_t     = (bf16*)p;  p += 4194304;      // (8, 1024, 256) bf16
    bf16* w_in_b  = (bf16*)p;  p += 3145728;      // (6144, 256) bf16
    bf16* w_out_b = (bf16*)p;  p += 1048576;      // (256, 2048) bf16
    float* Z      = (float*)p; p += 256;          // 64 softmax denominators

    prep_convert<<<2048, 256, 0, stream>>>(w_in, w_out, w_in_b, w_out_b, Z, out);
    prep_xt<<<dim3(64, 8), 256, 0, stream>>>(x, x_t);

    // g1: M=1024(l) N=6144(o) K=256(c); epilogue emits Qsw/Ksw/Vsw directly.
    gemm_nt<<<dim3(48, 8, 8), 256, 0, stream>>>(
        x_t, w_in_b, nullptr,
        1024, 6144, 256, 256, 256, 0,
        1024L * 256, 0, 0, 0, 0, 0,
        1, 0, b_in, nullptr, SCALE, Qsw, Ksw, Vsw);

    // fused attention (1D grid, XCD-swizzled)
    attn_fused<<<1024, 256, 0, stream>>>(Qsw, Ksw, Vsw, out_tt, Z);

    // g4: split-K=2 atomic. z = n*2 + kc (H=2), K=1024/chunk, kiters=16.
    gemm_nt<<<dim3(8, 2, 16), 256, 0, stream>>>(
        w_out_b, out_tt, out,
        256, 1024, 1024, 2048, 2048, 1024,
        0, 1024, 1024L * 2048, 1024, 256L * 1024, 0,
        2, 4, b_out, Z, 1.0f, nullptr, nullptr, nullptr);
}

// Round 11
// 232.110 us; speedup vs baseline: 1.3755x; 1.0092x over previous
//
#include <hip/hip_runtime.h>
#include <hip/hip_bf16.h>

// MultiHeadAttention: x(8,256,32,32) -> qkv proj -> global-softmax attention -> out proj.
//   proj_qkv: (x_t . w_in + b_in) * SCALE -> fragment-swizzled Qsw/Ksw/Vsw.
//             Barrier-free: BOTH operands read as MFMA fragments straight from global
//             (Axw from prep_xt, Wsw from prep_convert), depth-3 register pipeline.
//   attn_fused (R10): out_tt = Sum_l exp(q.k) v  (unnormalized), Z[nh] = Sum exp.
//   g4 (gemm_nt mode 4): out = w_out . (out_tt/Z) + b_out, split-K=2 atomic.
// Global softmax: att ~ N(0,0.17^2) -> exp() without max-subtraction is safe.
// Fragment layouts (32x32x16, verified R7-R10): A/B lane: row=lane&31, k=(lane>>5)*8+j;
//   C/D: col=lane&31, row=(reg&3)+8*(reg>>2)+4*(lane>>5).
// Frag buffers: elem(rb,k-frag) tile = 512 bf16 contiguous; within: (row&31, k8)*8+(k&7).
// R11: g1 was a 4-kiter barrier-laced K-loop (~80us at 30% busy, 10us MFMA floor).
//      proj_qkv = fragment-direct, zero-barrier K-loop (the R9/R10-validated pattern).

typedef __bf16 bf16x8 __attribute__((ext_vector_type(8)));
typedef __bf16 bf16x4 __attribute__((ext_vector_type(4)));
typedef float f32x4 __attribute__((ext_vector_type(4)));
typedef float f32x16 __attribute__((ext_vector_type(16)));
typedef __hip_bfloat16 bf16;

__device__ __forceinline__ void async_copy16(const void* g, void* s) {
    __builtin_amdgcn_global_load_lds(
        (const __attribute__((address_space(1))) unsigned int*)g,
        (__attribute__((address_space(3))) unsigned int*)s, 16, 0, 0);
}

__device__ __forceinline__ bf16x8 scale8(bf16x8 v, float s) {
    bf16x8 r;
#pragma unroll
    for (int e = 0; e < 8; ++e) r[e] = (__bf16)((float)v[e] * s);
    return r;
}

// ---------------------------------------------------------------------------
// QKV projection, fragment-direct. Block = 128l x 128o; grid 3072 (XCD n = b&7).
// Per wave (2x2 of 64x64): 16 k-steps x 4 MFMA(32x32x16), operands global-coalesced,
// depth-3 register ping-pong, NO barriers until the epilogue swizzled emit.
__global__ __launch_bounds__(256)
void proj_qkv(const bf16* __restrict__ Axw, const bf16* __restrict__ Wsw,
              const float* __restrict__ bias, float scale,
              bf16* __restrict__ outQ, bf16* __restrict__ outK, bf16* __restrict__ outV)
{
    __shared__ __align__(16) bf16 smem[16384];

    const int tid  = threadIdx.x;
    const int wave = tid >> 6, lane = tid & 63;
    const int l31  = lane & 31, hw = lane >> 5;

    const int b  = blockIdx.x;
    const int n  = b & 7;                 // XCD affinity: one batch image per XCD
    const int s  = b >> 3;                // [0,384)
    const int ht = s / 48;
    const int r_ = s % 48;
    const int part = r_ % 6;              // 0,1=Q; 2,3=K; 4,5=V (d-halves)
    const int lt   = r_ / 6;              // l-tile of 128
    const int nh = n * 8 + ht;
    const int o0 = ht * 768 + part * 128; // global o column base
    const int d0 = (part & 1) * 128;

    const int wl = wave & 1, wo = wave >> 1;

    const bf16* Ap0 = Axw + ((long)(n * 32 + lt * 4 + wl * 2) * 16) * 512 + lane * 8;
    const bf16* Ap1 = Ap0 + 16 * 512;
    const bf16* Bp0 = Wsw + ((long)(ht * 24 + part * 4 + wo * 2) * 16) * 512 + lane * 8;
    const bf16* Bp1 = Bp0 + 16 * 512;

    bf16x8 Af[3][2], Bf[3][2];
#pragma unroll
    for (int p = 0; p < 3; ++p) {
        Af[p][0] = *(const bf16x8*)(Ap0 + p * 512);
        Af[p][1] = *(const bf16x8*)(Ap1 + p * 512);
        Bf[p][0] = *(const bf16x8*)(Bp0 + p * 512);
        Bf[p][1] = *(const bf16x8*)(Bp1 + p * 512);
    }

    f32x16 acc[2][2] = {};
#pragma unroll
    for (int k = 0; k < 16; ++k) {
        const int st = k % 3;
#pragma unroll
        for (int i = 0; i < 2; ++i)
#pragma unroll
            for (int j = 0; j < 2; ++j)
                acc[i][j] = __builtin_amdgcn_mfma_f32_32x32x16_bf16(
                    Af[st][i], Bf[st][j], acc[i][j], 0, 0, 0);
        if (k + 3 < 16) {
            Af[st][0] = *(const bf16x8*)(Ap0 + (k + 3) * 512);
            Af[st][1] = *(const bf16x8*)(Ap1 + (k + 3) * 512);
            Bf[st][0] = *(const bf16x8*)(Bp0 + (k + 3) * 512);
            Bf[st][1] = *(const bf16x8*)(Bp1 + (k + 3) * 512);
        }
    }

    // Epilogue: bias+scale, stage 128x128 swizzled, one barrier, b128 stores.
    float bv[2];
#pragma unroll
    for (int j = 0; j < 2; ++j) bv[j] = bias[o0 + wo * 64 + j * 32 + l31];

    if (part < 4) {
#pragma unroll
        for (int i = 0; i < 2; ++i)
#pragma unroll
            for (int j = 0; j < 2; ++j)
#pragma unroll
                for (int r = 0; r < 16; ++r) {
                    const int row = wl * 64 + i * 32 + (r & 3) + 8 * (r >> 2) + 4 * hw; // l
                    const int col = wo * 64 + j * 32 + l31;                              // d
                    const float v = (acc[i][j][r] + bv[j]) * scale;
                    const int c32 = col >> 3;
                    const int slot = (c32 & 8) | ((c32 & 7) ^ (row & 7));
                    smem[row * 128 + slot * 8 + (col & 7)] = __float2bfloat16(v);
                }
        __syncthreads();
        bf16* dst = (part < 2) ? outQ : outK;
#pragma unroll
        for (int k = 0; k < 8; ++k) {
            const int flat = k * 256 + tid;
            const int seg  = flat >> 6, ln = flat & 63;
            const int lb   = seg >> 3, wloc = seg & 7;
            const int row  = lb * 32 + (ln & 31);
            const int c32  = wloc * 2 + (ln >> 5);
            const int slot = (c32 & 8) | ((c32 & 7) ^ (row & 7));
            const f32x4 val = *(const f32x4*)(smem + row * 128 + slot * 8);
            const long addr = ((long)(nh * 32 + lt * 4 + lb) * 16 + (d0 >> 4) + wloc) * 512 + ln * 8;
            *(f32x4*)(dst + addr) = val;
        }
    } else {
        // V: stage transposed (rows d, chunks of l).
#pragma unroll
        for (int i = 0; i < 2; ++i)
#pragma unroll
            for (int j = 0; j < 2; ++j)
#pragma unroll
                for (int r = 0; r < 16; ++r) {
                    const int row = wl * 64 + i * 32 + (r & 3) + 8 * (r >> 2) + 4 * hw; // l
                    const int col = wo * 64 + j * 32 + l31;                              // d
                    const float v = (acc[i][j][r] + bv[j]) * scale;
                    const int rc = row >> 3;
                    const int slotT = (rc & 8) | ((rc & 7) ^ (col & 7));
                    smem[col * 128 + slotT * 8 + (row & 7)] = __float2bfloat16(v);
                }
        __syncthreads();
#pragma unroll
        for (int k = 0; k < 8; ++k) {
            const int flat = k * 256 + tid;
            const int seg  = flat >> 6, ln = flat & 63;
            const int kwl  = seg >> 2, g2l = seg & 3;
            const int dl   = g2l * 32 + (ln & 31);
            const int lc   = kwl * 2 + (ln >> 5);
            const int slotT = (lc & 8) | ((lc & 7) ^ (dl & 7));
            const f32x4 val = *(const f32x4*)(smem + dl * 128 + slotT * 8);
            const long addr = ((long)(nh * 64 + lt * 8 + kwl) * 8 + (d0 >> 5) + g2l) * 512 + ln * 8;
            *(f32x4*)(outV + addr) = val;
        }
    }
}

// ---------------------------------------------------------------------------
// Generic NT bf16 GEMM (kept for g4 only). 128x128 tile, BK=64, m97+R4 structure.
// mode 3: C=f32, acc + bias[row]
// mode 4: split-K atomic: atomicAdd(C, acc + (zh==0 ? bias[row] : 0));
//         B scaled by 1/Zp[zn*8 + zh*4 + k/256] during staging (H=2, K=1024/chunk)
__global__ __launch_bounds__(256)
void gemm_nt(const bf16* __restrict__ A, const bf16* __restrict__ B, void* __restrict__ Cvoid,
             int M, int N, int K, int lda, int ldb, int ldc,
             long asn, long ash, long bsn, long bsh, long csn, long csh,
             int H, int mode, const float* __restrict__ bias, const float* __restrict__ Zp,
             float scale)
{
    __shared__ __align__(16) bf16 smem[17408];
    bf16* Alds = smem;
    bf16* Blds = smem + 8192;

    const int tid  = threadIdx.x;
    const int wave = tid >> 6;
    const int lane = tid & 63;
    const int z  = blockIdx.z;
    const int zn = z / H, zh = z % H;

    const bf16* Ab = A + zn * asn + zh * ash;
    const bf16* Bb = B + zn * bsn + zh * bsh;

    const long tM = (long)blockIdx.y * 128;
    const long tN = (long)blockIdx.x * 128;

    const int wr   = (wave >> 1) * 64;
    const int wc   = (wave & 1) * 64;
    const int l15  = lane & 15;
    const int quad = lane >> 4;

    f32x4 acc[4][4] = {};

    const int kiters = K >> 6;
    const bool regB = (mode == 4);

#pragma unroll
    for (int i = 0; i < 4; ++i) {
        const int flat = i * 256 + tid;
        const int row  = flat >> 3;
        const int kcs  = (flat & 7) ^ (row & 7);
        async_copy16(Ab + (tM + row) * (long)lda + kcs * 8,
                     (char*)Alds + (long)(i * 256 + wave * 64) * 16);
        if (!regB) {
            async_copy16(Bb + (tN + row) * (long)ldb + kcs * 8,
                         (char*)Blds + (long)(i * 256 + wave * 64) * 16);
        }
    }
    if (regB) {
        const float zi0 = 1.0f / Zp[zn * 8 + zh * 4];
#pragma unroll
        for (int i = 0; i < 4; ++i) {
            const int flat = i * 256 + tid;
            const int row  = flat >> 3;
            const int kcs  = (flat & 7) ^ (row & 7);
            bf16x8 bv = *(const bf16x8*)(Bb + (tN + row) * (long)ldb + kcs * 8);
            *(bf16x8*)((char*)Blds + (long)flat * 16) = scale8(bv, zi0);
        }
    }

    bf16x8 pfA[4], pfB[4];
    for (int kt = 0; kt < kiters; ++kt) {
        __syncthreads();
        const bool has_next = (kt + 1 < kiters);
        float zin = 1.0f;
        if (has_next) {
            const long kof = (long)(kt + 1) * 64;
            if (regB) zin = 1.0f / Zp[zn * 8 + zh * 4 + ((kt + 1) >> 2)];
#pragma unroll
            for (int i = 0; i < 4; ++i) {
                const int flat = i * 256 + tid;
                const int row  = flat >> 3;
                const int kcs  = (flat & 7) ^ (row & 7);
                pfA[i] = *(const bf16x8*)(Ab + (tM + row) * (long)lda + kof + kcs * 8);
                pfB[i] = *(const bf16x8*)(Bb + (tN + row) * (long)ldb + kof + kcs * 8);
            }
        }
#pragma unroll
        for (int kk = 0; kk < 2; ++kk) {
            bf16x8 af[4], bfv[4];
#pragma unroll
            for (int i = 0; i < 4; ++i) {
                const int r = wr + i * 16 + l15;
                af[i] = *(const bf16x8*)(Alds + r * 64 + ((kk * 4 + quad) ^ (r & 7)) * 8);
            }
#pragma unroll
            for (int j = 0; j < 4; ++j) {
                const int r = wc + j * 16 + l15;
                bfv[j] = *(const bf16x8*)(Blds + r * 64 + ((kk * 4 + quad) ^ (r & 7)) * 8);
            }
#pragma unroll
            for (int i = 0; i < 4; ++i)
#pragma unroll
                for (int j = 0; j < 4; ++j)
                    acc[i][j] = __builtin_amdgcn_mfma_f32_16x16x32_bf16(af[i], bfv[j], acc[i][j], 0, 0, 0);
        }
        if (has_next) {
            __builtin_amdgcn_sched_barrier(0);
            __builtin_amdgcn_s_barrier();
            __builtin_amdgcn_sched_barrier(0);
#pragma unroll
            for (int i = 0; i < 4; ++i) {
                const int flat = i * 256 + tid;
                *(bf16x8*)((char*)Alds + (long)flat * 16) = pfA[i];
                *(bf16x8*)((char*)Blds + (long)flat * 16) = regB ? scale8(pfB[i], zin) : pfB[i];
            }
        }
    }

    float* C = (float*)Cvoid + zn * csn + zh * csh;
#pragma unroll
    for (int i = 0; i < 4; ++i)
#pragma unroll
        for (int j = 0; j < 4; ++j)
#pragma unroll
            for (int r = 0; r < 4; ++r) {
                const long row = tM + wr + i * 16 + quad * 4 + r;
                const long col = tN + wc + j * 16 + l15;
                if (mode == 4) {
                    const float v = acc[i][j][r] + (zh == 0 ? bias[row] : 0.0f);
                    atomicAdd(&C[row * (long)ldc + col], v);
                } else {
                    C[row * (long)ldc + col] = acc[i][j][r] + bias[row];
                }
            }
}

// ---------------------------------------------------------------------------
// Fused attention v6 (R10, unchanged). Block = (64-key m-tile, nh); grid 1024.
__global__ __launch_bounds__(256, 2)
void attn_fused(const bf16* __restrict__ Qsw, const bf16* __restrict__ Ksw,
                const bf16* __restrict__ Vsw, bf16* __restrict__ out_tt,
                float* __restrict__ Z)
{
    __shared__ __align__(16) bf16 smem[16904];
    bf16* Ps  = smem;
    float* Zs = (float*)(smem + 16896);

    const int tid  = threadIdx.x;
    const int wave = tid >> 6, lane = tid & 63;
    const int l31  = lane & 31, hw = lane >> 5;

    const int b   = blockIdx.x;
    const int xcd = b & 7, s = b >> 3;
    const int nh  = xcd * 8 + (s >> 4);
    const int mt  = s & 15;
    const int n   = nh >> 3, h = nh & 7;
    const long m0 = (long)mt * 64;

    const int wl = wave & 1, wm = wave >> 1;

    bf16x8 Kf[16];
    {
        const bf16* kb = Ksw + ((long)(nh * 32 + mt * 2 + wm) * 16) * 512 + lane * 8;
#pragma unroll
        for (int w = 0; w < 16; ++w)
            Kf[w] = *(const bf16x8*)(kb + w * 512);
    }
    bf16x8 Qc[16];
    {
        const bf16* qb = Qsw + ((long)(nh * 32 + wl) * 16) * 512 + lane * 8;
#pragma unroll
        for (int w = 0; w < 16; ++w)
            Qc[w] = *(const bf16x8*)(qb + w * 512);
    }

    f32x16 accO[2][2] = {};
    float zsum = 0.0f;

    for (int lt = 0; lt < 16; ++lt) {
        bf16x8 vf[4][2];
#pragma unroll
        for (int kw = 0; kw < 4; ++kw)
#pragma unroll
            for (int dt = 0; dt < 2; ++dt)
                vf[kw][dt] = *(const bf16x8*)(
                    Vsw + ((long)(nh * 64 + lt * 4 + kw) * 8 + wave * 2 + dt) * 512 + lane * 8);

        f32x16 a0 = {}, a1 = {};
#pragma unroll
        for (int w = 0; w < 16; w += 2) {
            a0 = __builtin_amdgcn_mfma_f32_32x32x16_bf16(Qc[w], Kf[w], a0, 0, 0, 0);
            a1 = __builtin_amdgcn_mfma_f32_32x32x16_bf16(Qc[w + 1], Kf[w + 1], a1, 0, 0, 0);
        }

        bf16* Pb = Ps + (lt & 1) * 6144;
#pragma unroll
        for (int g = 0; g < 4; ++g) {
            bf16x4 pk;
#pragma unroll
            for (int e = 0; e < 4; ++e) {
                const float v = __expf(a0[g * 4 + e] + a1[g * 4 + e]);
                zsum += v;
                pk[e] = (__bf16)v;
            }
            const int l  = wl * 32 + 4 * hw + 8 * g;
            const int kw = l >> 4, off = l & 15;
            *(bf16x4*)(Pb + kw * 1536 + (wm * 32 + l31) * 24 + off) = pk;
        }

        __syncthreads();

        if (lt < 15) {
            const bf16* qn = Qsw + ((long)(nh * 32 + (lt + 1) * 2 + wl) * 16) * 512 + lane * 8;
#pragma unroll
            for (int w = 0; w < 16; ++w)
                Qc[w] = *(const bf16x8*)(qn + w * 512);
        }

#pragma unroll
        for (int kw = 0; kw < 4; ++kw) {
            bf16x8 pf[2];
#pragma unroll
            for (int mh = 0; mh < 2; ++mh)
                pf[mh] = *(const bf16x8*)(Pb + kw * 1536 + (mh * 32 + l31) * 24 + hw * 8);
#pragma unroll
            for (int mh = 0; mh < 2; ++mh)
#pragma unroll
                for (int dt = 0; dt < 2; ++dt)
                    accO[mh][dt] = __builtin_amdgcn_mfma_f32_32x32x16_bf16(
                        pf[mh], vf[kw][dt], accO[mh][dt], 0, 0, 0);
        }
    }

    __syncthreads();

#pragma unroll
    for (int o = 32; o > 0; o >>= 1) zsum += __shfl_down(zsum, o);
    if (lane == 0) Zs[wave] = zsum;

    bf16* Cs = smem;
#pragma unroll
    for (int mh = 0; mh < 2; ++mh)
#pragma unroll
        for (int dt = 0; dt < 2; ++dt)
#pragma unroll
            for (int r = 0; r < 16; ++r) {
                const int m = mh * 32 + (r & 3) + 8 * (r >> 2) + 4 * hw;
                const int d = wave * 64 + dt * 32 + l31;
                Cs[m * 264 + d] = __float2bfloat16(accO[mh][dt][r]);
            }
    __syncthreads();
    if (tid == 0) atomicAdd(Z + nh, (Zs[0] + Zs[1]) + (Zs[2] + Zs[3]));

    bf16* Ob = out_tt + (long)n * 2097152 + m0 * 2048 + h * 256;
#pragma unroll
    for (int k = 0; k < 8; ++k) {
        const int flat = k * 256 + tid;
        const int row  = flat >> 5;
        const int c    = flat & 31;
        const f32x4 val = *(const f32x4*)((const char*)Cs + row * 528 + c * 16);
        *(f32x4*)((char*)(Ob + (long)row * 2048) + c * 16) = val;
    }
}

// ---------------------------------------------------------------------------
// Weights: w_in -> fragment-swizzled Wsw; w_out -> linear bf16. Zero Z and d_out.
__global__ void prep_convert(const float* __restrict__ w_in, const float* __restrict__ w_out,
                             bf16* __restrict__ Wsw, bf16* __restrict__ w_out_b,
                             float* __restrict__ Z, float* __restrict__ out)
{
    const long gid = (long)blockIdx.x * 256 + threadIdx.x;
    if (blockIdx.x == 0 && threadIdx.x < 64) Z[threadIdx.x] = 0.0f;
    const f32x4 z4 = {0.0f, 0.0f, 0.0f, 0.0f};
    if (gid < 524288) ((f32x4*)out)[gid] = z4;
    const long n1 = 6144L * 256;
    const long n2 = 256L * 2048;
    const long stride = (long)gridDim.x * 256;
    for (long i = gid; i < n1; i += stride) {
        const int o = (int)(i >> 8), c = (int)(i & 255);
        const long addr = ((long)((o >> 5) * 16 + (c >> 4))) * 512
                        + ((o & 31) + 32 * ((c >> 3) & 1)) * 8 + (c & 7);
        Wsw[addr] = __float2bfloat16(w_in[i]);
    }
    for (long i = gid; i < n2; i += stride) w_out_b[i] = __float2bfloat16(w_out[i]);
}

// x (n, 256 c, 1024 l) f32 -> Axw fragment layout (rows l, K=c), 64x64 LDS tiles.
__global__ void prep_xt(const float* __restrict__ x, bf16* __restrict__ Axw)
{
    __shared__ float tile[64][65];
    const int b = blockIdx.x;
    const int n = blockIdx.y;
    const int ct = b & 3, lt = b >> 2;
    const int t = threadIdx.x;
    const float* xp = x + (long)n * 256 * 1024;
#pragma unroll
    for (int i = 0; i < 16; ++i) {
        const int flat = i * 256 + t;
        const int cl = flat >> 6, ll = flat & 63;
        tile[cl][ll] = xp[(long)(ct * 64 + cl) * 1024 + lt * 64 + ll];
    }
    __syncthreads();
#pragma unroll
    for (int i = 0; i < 16; ++i) {
        const int flat = i * 256 + t;
        const int lr = flat >> 6, cr = flat & 63;
        const int l = lt * 64 + lr, c = ct * 64 + cr;
        const long addr = ((long)((n * 32 + (l >> 5)) * 16 + (c >> 4))) * 512
                        + ((l & 31) + 32 * ((c >> 3) & 1)) * 8 + (c & 7);
        Axw[addr] = __float2bfloat16(tile[cr][lr]);
    }
}

extern "C" void kernel_launch(void* const* d_in, const int* in_sizes, int n_in,
                              void* d_out, int out_size, void* d_ws, size_t ws_size,
                              hipStream_t stream)
{
    const float* x     = (const float*)d_in[0];
    const float* w_in  = (const float*)d_in[1];
    const float* b_in  = (const float*)d_in[2];
    const float* w_out = (const float*)d_in[3];
    const float* b_out = (const float*)d_in[4];
    float* out = (float*)d_out;

    const float SCALE = 0.10416666666666667f;     // 1/16 * sqrt(6400/2304) = 5/48

    char* p = (char*)d_ws;
    bf16* Qsw     = (bf16*)p;  p += 33554432;     // fragment-swizzled Q
    bf16* Ksw     = (bf16*)p;  p += 33554432;     // fragment-swizzled K
    bf16* Vsw     = (bf16*)p;  p += 33554432;     // fragment-swizzled V (transposed)
    bf16* out_tt  = (bf16*)p;  p += 33554432;     // (8, 1024, 2048) bf16 (unnormalized)
    bf16* Axw     = (bf16*)p;  p += 4194304;      // x_t fragment layout
    bf16* Wsw     = (bf16*)p;  p += 3145728;      // w_in fragment layout
    bf16* w_out_b = (bf16*)p;  p += 1048576;      // (256, 2048) bf16 linear
    float* Z      = (float*)p; p += 256;          // 64 softmax denominators

    prep_convert<<<2048, 256, 0, stream>>>(w_in, w_out, Wsw, w_out_b, Z, out);
    prep_xt<<<dim3(64, 8), 256, 0, stream>>>(x, Axw);

    // g1: fragment-direct projection, 3072 blocks (8n x 8ht x 6part x 8lt).
    proj_qkv<<<3072, 256, 0, stream>>>(Axw, Wsw, b_in, SCALE, Qsw, Ksw, Vsw);

    // fused attention (1D grid, XCD-swizzled)
    attn_fused<<<1024, 256, 0, stream>>>(Qsw, Ksw, Vsw, out_tt, Z);

    // g4: split-K=2 atomic. z = n*2 + kc (H=2), K=1024/chunk, kiters=16.
    gemm_nt<<<dim3(8, 2, 16), 256, 0, stream>>>(
        w_out_b, out_tt, out,
        256, 1024, 1024, 2048, 2048, 1024,
        0, 1024, 1024L * 2048, 1024, 256L * 1024, 0,
        2, 4, b_out, Z, 1.0f);
}